// Round 10
// baseline (319.985 us; speedup 1.0000x reference)
//
#include <hip/hip_runtime.h>
#include <stdint.h>

#define NB 4
#define LS 1024
#define HH 16
#define DHD 64
#define DM 1024
#define DF 4096
#define QKS 2048  // row stride of combined QK activation buffer

typedef unsigned short u16;
typedef __attribute__((ext_vector_type(4))) float f32x4;
typedef __attribute__((ext_vector_type(8))) __bf16 bf16x8;
typedef __attribute__((ext_vector_type(8))) unsigned short u16x8;

__device__ __forceinline__ u16 f2bf(float f) {
  union { float f; uint32_t u; } v; v.f = f;
  uint32_t u = v.u;
  return (u16)((u + 0x7fffu + ((u >> 16) & 1u)) >> 16);
}

__device__ __forceinline__ bf16x8 ldb8(const u16* p) {
  u16x8 r = *(const u16x8*)p;
  return __builtin_bit_cast(bf16x8, r);
}

__device__ __forceinline__ void gload_lds16(const u16* g, u16* l) {
  __builtin_amdgcn_global_load_lds((const __attribute__((address_space(1))) void*)g,
                                   (__attribute__((address_space(3))) void*)l,
                                   16, 0, 0);
}

#define WAITV8() asm volatile("s_waitcnt vmcnt(8)" ::: "memory")
#define WAITV0() asm volatile("s_waitcnt vmcnt(0)" ::: "memory")
#define WAITLGKM() asm volatile("s_waitcnt lgkmcnt(0)" ::: "memory")
#define PHASE_BARRIER()                        \
  do {                                         \
    WAITLGKM();                                \
    __builtin_amdgcn_sched_barrier(0);         \
    __builtin_amdgcn_s_barrier();              \
    __builtin_amdgcn_sched_barrier(0);         \
  } while (0)

// ---------------------------------------------------------------------------
// prep: decode padding_mask (byte/int32/float agnostic). Grid = NB blocks;
// each block scans the shared prefix for the byte-encoding flag (cross-sample
// evidence needed: an all-False sample is ambiguous alone), then counts its
// own sample's non-padded keys.
// ---------------------------------------------------------------------------
__global__ void prep_kernel(const uint32_t* __restrict__ pm, int* lens, float* iscl) {
  __shared__ int flagByte;
  __shared__ int red[256];
  const int tid = threadIdx.x, n = blockIdx.x;
  if (tid == 0) flagByte = 0;
  __syncthreads();
  int f = 0;
  for (int w = tid; w < (NB * LS) / 4; w += 256) {
    uint32_t u = pm[w];
    if (u != 0u && u != 1u && u != 0x3f800000u) f = 1;  // packed-byte pattern
  }
  if (f) atomicOr(&flagByte, 1);
  __syncthreads();
  int c = 0;
  if (flagByte) {
    const uint8_t* pb = (const uint8_t*)pm;
    for (int l = tid; l < LS; l += 256) c += (pb[n * LS + l] == 0) ? 1 : 0;
  } else {
    for (int l = tid; l < LS; l += 256) c += (pm[n * LS + l] == 0) ? 1 : 0;
  }
  red[tid] = c;
  __syncthreads();
  for (int s = 128; s > 0; s >>= 1) {
    if (tid < s) red[tid] += red[tid + s];
    __syncthreads();
  }
  if (tid == 0) { lens[n] = red[0]; iscl[n] = 1.0f / sqrtf((float)red[0]); }
}

// ---------------------------------------------------------------------------
// fused fp32 -> bf16 convert for all 10 tensors (one launch)
// ---------------------------------------------------------------------------
__global__ void cvt_all(const float* s0, u16* d0, const float* s1, u16* d1,
                        const float* s2, u16* d2, const float* s3, u16* d3,
                        const float* s4, u16* d4, const float* s5, u16* d5,
                        const float* s6, u16* d6, const float* s7, u16* d7,
                        const float* s8, u16* d8, const float* s9, u16* d9) {
  const int total = 5767168;  // float4 units
  int i = blockIdx.x * 256 + threadIdx.x;
  for (; i < total; i += gridDim.x * 256) {
    const float* s; u16* d; int j;
    if (i < 1048576)      { s = s0; d = d0; j = i; }
    else if (i < 2097152) { s = s1; d = d1; j = i - 1048576; }
    else if (i < 2359296) { s = s2; d = d2; j = i - 2097152; }
    else if (i < 2621440) { s = s3; d = d3; j = i - 2359296; }
    else if (i < 2883584) { s = s4; d = d4; j = i - 2621440; }
    else if (i < 3145728) { s = s5; d = d5; j = i - 2883584; }
    else if (i < 3407872) { s = s6; d = d6; j = i - 3145728; }
    else if (i < 3670016) { s = s7; d = d7; j = i - 3407872; }
    else if (i < 4718592) { s = s8; d = d8; j = i - 3670016; }
    else                  { s = s9; d = d9; j = i - 4718592; }
    float4 fv = ((const float4*)s)[j];
    ushort4 o;
    o.x = f2bf(fv.x); o.y = f2bf(fv.y); o.z = f2bf(fv.z); o.w = f2bf(fv.w);
    ((ushort4*)d)[j] = o;
  }
}

// ---------------------------------------------------------------------------
// 8-phase 256x256 GEMM: 512 thr (8 waves, 2Mx4N), BK=64 in two k-halves.
// Schedule frozen from R6 (single barrier/phase, counted vmcnt). Grids are
// kept at <=256 blocks (exactly one dispatch round at 1 block/CU).
// MODE 0: FFN1 relu(x+bias)->bf16. MODE 1: FFN2 split-K f32 partial.
// MODE 2: mega projection, 16 bn-tiles (QKa / VtA / QKb K-part).
// ---------------------------------------------------------------------------
template <int MODE>
__global__ __launch_bounds__(512, 2) void gemm8(
    const u16* __restrict__ P0, const u16* __restrict__ P1,
    const u16* __restrict__ PW, const float* __restrict__ bias,
    void* __restrict__ O0, void* __restrict__ O1,
    void* __restrict__ O2, void* __restrict__ O3) {
  extern __shared__ u16 lds[];  // 65536 u16 = 128 KiB
  constexpr int NT = 16;
  const int bm = blockIdx.x;
  const int tid = threadIdx.x;
  const int wid = tid >> 6, lane = tid & 63;
  const int lrow = lane & 15, lgrp = lane >> 4;
  const int wm = wid >> 2, wn = wid & 3;

  const u16* Asrc; const u16* Bsrc; int lda, ldb;
  if constexpr (MODE == 0) {
    Asrc = P0 + (size_t)bm * 256 * DM; lda = DM;
    Bsrc = PW + (size_t)blockIdx.y * 256 * DM; ldb = DM;
  } else if constexpr (MODE == 1) {
    const int z = blockIdx.z;
    Asrc = P0 + (size_t)bm * 256 * DF + z * 1024; lda = DF;
    Bsrc = PW + (size_t)blockIdx.y * 256 * DF + z * 1024; ldb = DF;
  } else {
    const int bnt = blockIdx.y;
    Asrc = (bnt < 12 ? P0 : P1) + (size_t)bm * 256 * DM; lda = DM;
    const int wrow = (bnt < 12) ? bnt * 256 : 4096 + (bnt - 12) * 256;
    Bsrc = PW + (size_t)wrow * DM; ldb = DM;
  }

  int srow[2], skk[2];
#pragma unroll
  for (int i = 0; i < 2; i++) {
    const int c = (i * 8 + wid) * 64 + lane;
    const int pair = c >> 3;
    const int ue = ((c & 7) * 8) ^ ((pair & 7) << 3);
    srow[i] = pair * 2 + (ue >> 5);
    skk[i] = ue & 31;
  }
  const int dslot0 = wid * 512;
  const int dslot1 = (8 + wid) * 512;

  f32x4 acc[2][4][4] = {};

  auto STAGE_A = [&](int kt, int buf, int kh) {
    const int ks = kt < NT ? kt : NT - 1;  // clamped dummy keeps vmcnt uniform
    gload_lds16(Asrc + (size_t)srow[0] * lda + ks * 64 + kh * 32 + skk[0],
                lds + buf * 16384 + kh * 8192 + dslot0);
    gload_lds16(Asrc + (size_t)srow[1] * lda + ks * 64 + kh * 32 + skk[1],
                lds + buf * 16384 + kh * 8192 + dslot1);
  };
  auto STAGE_B = [&](int kt, int buf, int kh) {
    const int ks = kt < NT ? kt : NT - 1;
    gload_lds16(Bsrc + (size_t)srow[0] * ldb + ks * 64 + kh * 32 + skk[0],
                lds + 32768 + buf * 16384 + kh * 8192 + dslot0);
    gload_lds16(Bsrc + (size_t)srow[1] * ldb + ks * 64 + kh * 32 + skk[1],
                lds + 32768 + buf * 16384 + kh * 8192 + dslot1);
  };
  auto LDA = [&](int buf, int kh, int mh, bf16x8* a) {
#pragma unroll
    for (int m = 0; m < 4; m++) {
      const int row = wm * 128 + mh * 64 + m * 16 + lrow;
      const int idx = buf * 16384 + kh * 8192 + (row >> 1) * 64 +
                      ((((row & 1) << 5) + (lgrp << 3)) ^ (((row >> 1) & 7) << 3));
      a[m] = ldb8(lds + idx);
    }
  };
  auto LDB = [&](int buf, int kh, bf16x8* b) {
#pragma unroll
    for (int nn = 0; nn < 4; nn++) {
      const int row = wn * 64 + nn * 16 + lrow;
      const int idx = 32768 + buf * 16384 + kh * 8192 + (row >> 1) * 64 +
                      ((((row & 1) << 5) + (lgrp << 3)) ^ (((row >> 1) & 7) << 3));
      b[nn] = ldb8(lds + idx);
    }
  };
  auto MFMA16 = [&](f32x4 (&a4)[4][4], bf16x8* af, bf16x8* bk) {
    __builtin_amdgcn_s_setprio(1);
#pragma unroll
    for (int m = 0; m < 4; m++)
#pragma unroll
      for (int nn = 0; nn < 4; nn++)
        a4[m][nn] = __builtin_amdgcn_mfma_f32_16x16x32_bf16(af[m], bk[nn], a4[m][nn], 0, 0, 0);
    __builtin_amdgcn_s_setprio(0);
  };

  // prologue: 6 units (tile0 kh0+kh1, tile1 kh0); confirm tile0 kh0 (2 units)
  STAGE_A(0, 0, 0); STAGE_B(0, 0, 0);
  STAGE_A(0, 0, 1); STAGE_B(0, 0, 1);
  STAGE_A(1, 1, 0); STAGE_B(1, 1, 0);
  WAITV8();
  __builtin_amdgcn_s_barrier();
  __builtin_amdgcn_sched_barrier(0);

  for (int t = 0; t < NT; t++) {
    const int b = t & 1;
    bf16x8 af[4], bk[4];
    // ---- P1 (kh0, mh0)
    LDA(b, 0, 0, af); LDB(b, 0, bk);
    STAGE_A(t + 1, b ^ 1, 1);
    PHASE_BARRIER();
    MFMA16(acc[0], af, bk);
    // ---- P2 (kh0, mh1)
    LDA(b, 0, 1, af);
    STAGE_B(t + 1, b ^ 1, 1);
    WAITV8();
    PHASE_BARRIER();
    MFMA16(acc[1], af, bk);
    // ---- P3 (kh1, mh0)
    LDA(b, 1, 0, af); LDB(b, 1, bk);
    STAGE_A(t + 2, b, 0);
    PHASE_BARRIER();
    MFMA16(acc[0], af, bk);
    // ---- P4 (kh1, mh1)
    LDA(b, 1, 1, af);
    STAGE_B(t + 2, b, 0);
    WAITV8();
    PHASE_BARRIER();
    MFMA16(acc[1], af, bk);
  }
  WAITV0();  // drain dummy stages before block exit

  // ---- epilogue
#pragma unroll
  for (int mh = 0; mh < 2; mh++)
#pragma unroll
    for (int m = 0; m < 4; m++) {
      const int grow0 = bm * 256 + wm * 128 + mh * 64 + m * 16 + lgrp * 4;
#pragma unroll
      for (int nn = 0; nn < 4; nn++) {
        const int col_l = wn * 64 + nn * 16 + lrow;
        f32x4 v = acc[mh][m][nn];
        if constexpr (MODE == 0) {
          const int col = blockIdx.y * 256 + col_l;
          const float bv = bias[col];
#pragma unroll
          for (int r = 0; r < 4; r++) {
            float x = v[r] + bv;
            x = x > 0.0f ? x : 0.0f;
            ((u16*)O0)[(size_t)(grow0 + r) * DF + col] = f2bf(x);
          }
        } else if constexpr (MODE == 1) {
          float* C = (float*)O0 + (size_t)blockIdx.z * ((size_t)NB * LS * DM);
          const int col = blockIdx.y * 256 + col_l;
#pragma unroll
          for (int r = 0; r < 4; r++) C[(size_t)(grow0 + r) * DM + col] = v[r];
        } else {
          const int bnt = blockIdx.y;
          const int nidx = grow0 >> 10, l0 = grow0 & 1023;
          if (bnt < 8) {
            const int col = bnt * 256 + col_l;
#pragma unroll
            for (int r = 0; r < 4; r++)
              ((u16*)O0)[(size_t)(grow0 + r) * QKS + col] = f2bf(v[r]);
          } else if (bnt < 12) {
            const int vc = (bnt - 8) * 256 + col_l;
            ushort4 o;
            o.x = f2bf(v[0]); o.y = f2bf(v[1]); o.z = f2bf(v[2]); o.w = f2bf(v[3]);
            *(ushort4*)((u16*)O1 + (((size_t)(nidx * HH + (vc >> 6)) * DHD + (vc & 63)) << 10) + l0) = o;
          } else {
            const int col = 1024 + (bnt - 12) * 256 + col_l;
#pragma unroll
            for (int r = 0; r < 4; r++)
              ((u16*)O2)[(size_t)(grow0 + r) * QKS + col] = f2bf(v[r]);
          }
        }
      }
    }
}

// ---------------------------------------------------------------------------
// Stage-B Q projection + V_B projection in ONE 512-block dispatch (m97 128^2,
// 4 waves, 2 blocks/CU co-resident -> one round).
//   bn < 8 : Q2 = Ybf(post-LN1) @ Wq2^T -> QKb cols 0..1023 (stride QKS)
//   bn >= 8: V_B = Ebf @ Wv2^T -> VtB[n][h][d][l] (transposed per-head)
// ---------------------------------------------------------------------------
__global__ __launch_bounds__(256) void gemm_qv(const u16* __restrict__ Ya,
                                               const u16* __restrict__ Ea,
                                               const u16* __restrict__ Wq,
                                               const u16* __restrict__ Wv,
                                               u16* __restrict__ QKb,
                                               u16* __restrict__ VtB) {
  __shared__ u16 Al[128 * 32];
  __shared__ u16 Bl[128 * 32];
  const int tid = threadIdx.x;
  const int bm = blockIdx.x, bnr = blockIdx.y;
  const bool isV = bnr >= 8;
  const int bn = isV ? bnr - 8 : bnr;
  const int wave = tid >> 6, lane = tid & 63;
  const int lrow = lane & 15, lgrp = lane >> 4;
  const int wr = (wave >> 1) * 64, wc = (wave & 1) * 64;
  f32x4 acc[4][4] = {};
  const u16* Ab = (isV ? Ea : Ya) + (size_t)bm * 128 * DM;
  const u16* Bb = (isV ? Wv : Wq) + (size_t)bn * 128 * DM;
  {
    const int c0 = wave, c1 = wave + 4;
    const int r0 = c0 * 16 + (lane >> 2), r1 = c1 * 16 + (lane >> 2);
    const int scc = (lane & 3) * 8;
    const u16* Ag0 = Ab + (size_t)r0 * DM + scc;
    const u16* Ag1 = Ab + (size_t)r1 * DM + scc;
    const u16* Bg0 = Bb + (size_t)r0 * DM + scc;
    const u16* Bg1 = Bb + (size_t)r1 * DM + scc;
    u16* Ad0 = Al + c0 * 512;
    u16* Ad1 = Al + c1 * 512;
    u16* Bd0 = Bl + c0 * 512;
    u16* Bd1 = Bl + c1 * 512;
    for (int kb = 0; kb < DM; kb += 32) {
      gload_lds16(Ag0, Ad0);
      gload_lds16(Ag1, Ad1);
      gload_lds16(Bg0, Bd0);
      gload_lds16(Bg1, Bd1);
      Ag0 += 32; Ag1 += 32; Bg0 += 32; Bg1 += 32;
      __syncthreads();
      bf16x8 af[4], bfr[4];
#pragma unroll
      for (int m = 0; m < 4; m++) af[m] = ldb8(Al + (wr + m * 16 + lrow) * 32 + lgrp * 8);
#pragma unroll
      for (int nn = 0; nn < 4; nn++) bfr[nn] = ldb8(Bl + (wc + nn * 16 + lrow) * 32 + lgrp * 8);
#pragma unroll
      for (int m = 0; m < 4; m++)
#pragma unroll
        for (int nn = 0; nn < 4; nn++)
          acc[m][nn] = __builtin_amdgcn_mfma_f32_16x16x32_bf16(af[m], bfr[nn], acc[m][nn], 0, 0, 0);
      __syncthreads();
    }
  }
#pragma unroll
  for (int m = 0; m < 4; m++) {
    const int row0 = bm * 128 + wr + m * 16 + lgrp * 4;
    const int nidx = row0 >> 10, l0 = row0 & (LS - 1);
#pragma unroll
    for (int nn = 0; nn < 4; nn++) {
      const int col = bn * 128 + wc + nn * 16 + lrow;
      if (!isV) {
#pragma unroll
        for (int r = 0; r < 4; r++)
          QKb[(size_t)(row0 + r) * QKS + col] = f2bf(acc[m][nn][r]);
      } else {
        const int hh = col >> 6, dd = col & 63;
        ushort4 o;
        o.x = f2bf(acc[m][nn][0]); o.y = f2bf(acc[m][nn][1]);
        o.z = f2bf(acc[m][nn][2]); o.w = f2bf(acc[m][nn][3]);
        *(ushort4*)(VtB + (((size_t)(nidx * HH + hh) * DHD + dd) << 10) + l0) = o;
      }
    }
  }
}

// ---------------------------------------------------------------------------
// Flash attention. Grid (L/64, H, N), 256 threads = 4 waves x 16 q-rows.
// ---------------------------------------------------------------------------
template <bool CAUSAL>
__global__ __launch_bounds__(256) void attn_kernel(const u16* __restrict__ QK,
                                                   const u16* __restrict__ Vt,
                                                   float* __restrict__ Out,
                                                   const int* __restrict__ lens,
                                                   const float* __restrict__ iscl) {
  __shared__ u16 Kl[64 * 72];
  __shared__ u16 Vl[64 * 72];
  __shared__ u16 Pl[4][16 * 72];
  const int n = blockIdx.z, h = blockIdx.y, qb = blockIdx.x * 64;
  const int tid = threadIdx.x, wave = tid >> 6, lane = tid & 63;
  const int lrow = lane & 15, lgrp = lane >> 4;
  const int len = lens[n];
  const float isc = iscl[n];
  const int qrow = qb + wave * 16 + lrow;
  const u16* qptr = QK + ((size_t)(n * LS + qrow)) * QKS + h * DHD + lgrp * 8;
  bf16x8 qf0 = ldb8(qptr);
  bf16x8 qf1 = ldb8(qptr + 32);
  f32x4 oacc[4] = {};
  float m_run[4], l_run[4];
#pragma unroll
  for (int r = 0; r < 4; r++) { m_run[r] = -1e30f; l_run[r] = 0.0f; }
  const int kend = CAUSAL ? (len < qb + 64 ? len : qb + 64) : len;
  const int srow = tid >> 3, sc = (tid & 7) * 8;
  const u16* kg_base = QK + 1024 + ((size_t)(n * LS)) * QKS + h * DHD + sc;
  const u16* vg_base = Vt + ((size_t)((n * HH + h) * DHD) + srow) * LS + sc;
  u16* pw = Pl[wave];
  for (int kb = 0; kb < kend; kb += 64) {
    __syncthreads();
#pragma unroll
    for (int i = 0; i < 2; i++) {
      const int row = srow + i * 32;
      u16x8 kv = *(const u16x8*)(kg_base + (size_t)(kb + row) * QKS);
      *(u16x8*)(Kl + row * 72 + sc) = kv;
      u16x8 vv = *(const u16x8*)(vg_base + (size_t)(i * 32) * LS + kb);
      *(u16x8*)(Vl + row * 72 + sc) = vv;
    }
    __syncthreads();
    f32x4 s[4];
#pragma unroll
    for (int st = 0; st < 4; st++) {
      const u16* kr = Kl + (st * 16 + lrow) * 72 + lgrp * 8;
      bf16x8 kf0 = ldb8(kr);
      bf16x8 kf1 = ldb8(kr + 32);
      f32x4 z = {};
      z = __builtin_amdgcn_mfma_f32_16x16x32_bf16(qf0, kf0, z, 0, 0, 0);
      s[st] = __builtin_amdgcn_mfma_f32_16x16x32_bf16(qf1, kf1, z, 0, 0, 0);
    }
    const int q_r = qb + wave * 16 + lgrp * 4;
#pragma unroll
    for (int st = 0; st < 4; st++) {
      const int k = kb + st * 16 + lrow;
#pragma unroll
      for (int r = 0; r < 4; r++) {
        float v = s[st][r] * isc;
        bool ok = (k < len) && (!CAUSAL || k <= q_r + r);
        s[st][r] = ok ? v : -1e30f;
      }
    }
#pragma unroll
    for (int r = 0; r < 4; r++) {
      float mx = fmaxf(fmaxf(s[0][r], s[1][r]), fmaxf(s[2][r], s[3][r]));
      mx = fmaxf(mx, __shfl_xor(mx, 1));
      mx = fmaxf(mx, __shfl_xor(mx, 2));
      mx = fmaxf(mx, __shfl_xor(mx, 4));
      mx = fmaxf(mx, __shfl_xor(mx, 8));
      float mn = fmaxf(m_run[r], mx);
      float fac = __expf(m_run[r] - mn);
      m_run[r] = mn;
      float sm = 0.0f;
#pragma unroll
      for (int st = 0; st < 4; st++) {
        float p = __expf(s[st][r] - mn);
        s[st][r] = p;
        sm += p;
      }
      sm += __shfl_xor(sm, 1);
      sm += __shfl_xor(sm, 2);
      sm += __shfl_xor(sm, 4);
      sm += __shfl_xor(sm, 8);
      l_run[r] = l_run[r] * fac + sm;
#pragma unroll
      for (int dt = 0; dt < 4; dt++) oacc[dt][r] *= fac;
    }
#pragma unroll
    for (int st = 0; st < 4; st++)
#pragma unroll
      for (int r = 0; r < 4; r++)
        pw[(lgrp * 4 + r) * 72 + st * 16 + lrow] = f2bf(s[st][r]);
#pragma unroll
    for (int ks = 0; ks < 2; ks++) {
      bf16x8 pf = ldb8(pw + lrow * 72 + ks * 32 + lgrp * 8);
#pragma unroll
      for (int dt = 0; dt < 4; dt++) {
        bf16x8 vf = ldb8(Vl + (dt * 16 + lrow) * 72 + ks * 32 + lgrp * 8);
        oacc[dt] = __builtin_amdgcn_mfma_f32_16x16x32_bf16(pf, vf, oacc[dt], 0, 0, 0);
      }
    }
  }
#pragma unroll
  for (int r = 0; r < 4; r++) {
    float inv = 1.0f / l_run[r];
    const int row = qb + wave * 16 + lgrp * 4 + r;
    float* op = Out + ((size_t)(n * LS + row)) * DM + h * DHD;
#pragma unroll
    for (int dt = 0; dt < 4; dt++) op[dt * 16 + lrow] = oacc[dt][r] * inv;
  }
}

// ---------------------------------------------------------------------------
// residual + LayerNorm; emits f32 (next residual) and optional bf16
// ---------------------------------------------------------------------------
__global__ __launch_bounds__(256) void ln_kernel(const float* __restrict__ a,
                                                 const float* __restrict__ res,
                                                 const float* __restrict__ g,
                                                 const float* __restrict__ bta,
                                                 float* __restrict__ outf,
                                                 u16* __restrict__ outb) {
  const int row = blockIdx.x, tid = threadIdx.x;
  float4 x = ((const float4*)(a + (size_t)row * DM))[tid];
  float4 rr = ((const float4*)(res + (size_t)row * DM))[tid];
  x.x += rr.x; x.y += rr.y; x.z += rr.z; x.w += rr.w;
  float s = x.x + x.y + x.z + x.w;
  float s2 = x.x * x.x + x.y * x.y + x.z * x.z + x.w * x.w;
#pragma unroll
  for (int m = 1; m < 64; m <<= 1) { s += __shfl_xor(s, m); s2 += __shfl_xor(s2, m); }
  __shared__ float sm[8];
  const int wv = tid >> 6;
  if ((tid & 63) == 0) { sm[wv] = s; sm[4 + wv] = s2; }
  __syncthreads();
  s = sm[0] + sm[1] + sm[2] + sm[3];
  s2 = sm[4] + sm[5] + sm[6] + sm[7];
  const float mean = s * (1.0f / (float)DM);
  const float var = s2 * (1.0f / (float)DM) - mean * mean;
  const float inv = rsqrtf(var + 1e-5f);
  float4 gg = ((const float4*)g)[tid];
  float4 bb = ((const float4*)bta)[tid];
  float4 y;
  y.x = (x.x - mean) * inv * gg.x + bb.x;
  y.y = (x.y - mean) * inv * gg.y + bb.y;
  y.z = (x.z - mean) * inv * gg.z + bb.z;
  y.w = (x.w - mean) * inv * gg.w + bb.w;
  ((float4*)(outf + (size_t)row * DM))[tid] = y;
  if (outb) {
    ushort4 o;
    o.x = f2bf(y.x); o.y = f2bf(y.y); o.z = f2bf(y.z); o.w = f2bf(y.w);
    ((ushort4*)(outb + (size_t)row * DM))[tid] = o;
  }
}

// ---------------------------------------------------------------------------
// final LN: sums 4 split-K partials + bias + residual, then LayerNorm -> f32
// ---------------------------------------------------------------------------
__global__ __launch_bounds__(256) void ln_final(const float* __restrict__ part,
                                                const float* __restrict__ bias,
                                                const float* __restrict__ res,
                                                const float* __restrict__ g,
                                                const float* __restrict__ bta,
                                                float* __restrict__ outf) {
  const int row = blockIdx.x, tid = threadIdx.x;
  const size_t PS = (size_t)NB * LS * DM;
  float4 x = ((const float4*)(part + (size_t)row * DM))[tid];
  float4 p1 = ((const float4*)(part + PS + (size_t)row * DM))[tid];
  float4 p2 = ((const float4*)(part + 2 * PS + (size_t)row * DM))[tid];
  float4 p3 = ((const float4*)(part + 3 * PS + (size_t)row * DM))[tid];
  float4 bb4 = ((const float4*)bias)[tid];
  float4 rr = ((const float4*)(res + (size_t)row * DM))[tid];
  x.x += p1.x + p2.x + p3.x + bb4.x + rr.x;
  x.y += p1.y + p2.y + p3.y + bb4.y + rr.y;
  x.z += p1.z + p2.z + p3.z + bb4.z + rr.z;
  x.w += p1.w + p2.w + p3.w + bb4.w + rr.w;
  float s = x.x + x.y + x.z + x.w;
  float s2 = x.x * x.x + x.y * x.y + x.z * x.z + x.w * x.w;
#pragma unroll
  for (int m = 1; m < 64; m <<= 1) { s += __shfl_xor(s, m); s2 += __shfl_xor(s2, m); }
  __shared__ float sm[8];
  const int wv = tid >> 6;
  if ((tid & 63) == 0) { sm[wv] = s; sm[4 + wv] = s2; }
  __syncthreads();
  s = sm[0] + sm[1] + sm[2] + sm[3];
  s2 = sm[4] + sm[5] + sm[6] + sm[7];
  const float mean = s * (1.0f / (float)DM);
  const float var = s2 * (1.0f / (float)DM) - mean * mean;
  const float inv = rsqrtf(var + 1e-5f);
  float4 gg = ((const float4*)g)[tid];
  float4 bb = ((const float4*)bta)[tid];
  float4 y;
  y.x = (x.x - mean) * inv * gg.x + bb.x;
  y.y = (x.y - mean) * inv * gg.y + bb.y;
  y.z = (x.z - mean) * inv * gg.z + bb.z;
  y.w = (x.w - mean) * inv * gg.w + bb.w;
  ((float4*)(outf + (size_t)row * DM))[tid] = y;
}

// ---------------------------------------------------------------------------
extern "C" void kernel_launch(void* const* d_in, const int* in_sizes, int n_in,
                              void* d_out, int out_size, void* d_ws, size_t ws_size,
                              hipStream_t stream) {
  const float* enc = (const float*)d_in[0];
  const float* Yin = (const float*)d_in[1];
  const uint32_t* pmask = (const uint32_t*)d_in[3];
  const float* Wq1 = (const float*)d_in[4];
  const float* Wk1 = (const float*)d_in[5];
  const float* Wv1 = (const float*)d_in[6];
  const float* g1 = (const float*)d_in[7];
  const float* b1 = (const float*)d_in[8];
  const float* Wq2 = (const float*)d_in[9];
  const float* Wk2 = (const float*)d_in[10];
  const float* Wv2 = (const float*)d_in[11];
  const float* g2 = (const float*)d_in[12];
  const float* b2 = (const float*)d_in[13];
  const float* We = (const float*)d_in[14];
  const float* be = (const float*)d_in[15];
  const float* Wc = (const float*)d_in[16];
  const float* bc = (const float*)d_in[17];
  const float* g3 = (const float*)d_in[18];
  const float* b3 = (const float*)d_in[19];

  const size_t ACT = (size_t)NB * LS * DM;
  const size_t WSZ = (size_t)DM * DM;
  const size_t WFF = (size_t)DF * DM;
  const size_t HID = (size_t)NB * LS * DF;

  char* ws = (char*)d_ws;
  size_t off = 0;
  auto alloc = [&](size_t bytes) -> void* {
    void* p = ws + off;
    off += (bytes + 255) & ~(size_t)255;
    return p;
  };
  int* lens = (int*)alloc(64);
  float* iscl = (float*)alloc(64);
  u16* Ybf = (u16*)alloc(ACT * 2);
  u16* Ebf = (u16*)alloc(ACT * 2);
  u16* W6 = (u16*)alloc(WSZ * 6 * 2);
  u16* Web = (u16*)alloc(WFF * 2);
  u16* Wcb = (u16*)alloc(WFF * 2);
  size_t region0 = off;
  u16* QKa = (u16*)alloc((size_t)NB * LS * QKS * 2);
  u16* VtA = (u16*)alloc(ACT * 2);
  u16* QKb = (u16*)alloc((size_t)NB * LS * QKS * 2);
  u16* VtB = (u16*)alloc(ACT * 2);
  float* aout = (float*)alloc(ACT * 4);
  float* y2 = (float*)alloc(ACT * 4);
  float* part = (float*)(ws + region0);  // aliases region0 (dead by stage C)
  float* y3 = (float*)alloc(ACT * 4);
  u16* Hb = (u16*)alloc(HID * 2);

  prep_kernel<<<NB, 256, 0, stream>>>(pmask, lens, iscl);
  cvt_all<<<2048, 256, 0, stream>>>(Yin, Ybf, enc, Ebf,
                                    Wq1, W6 + 0 * WSZ, Wk1, W6 + 1 * WSZ,
                                    Wv1, W6 + 2 * WSZ, Wq2, W6 + 3 * WSZ,
                                    Wk2, W6 + 4 * WSZ, Wv2, W6 + 5 * WSZ,
                                    We, Web, Wc, Wcb);

  dim3 blk(256);
  // ---- fused projections: stage-A QKV + stage-B K (256 blocks = one round)
  gemm8<2><<<dim3(16, 16), 512, 131072, stream>>>(Ybf, Ebf, W6, nullptr,
                                                  QKa, VtA, QKb, VtB);
  // ---- stage A: masked self-attention + LN
  attn_kernel<true><<<dim3(16, 16, 4), blk, 0, stream>>>(QKa, VtA, aout, lens, iscl);
  ln_kernel<<<NB * LS, 256, 0, stream>>>(aout, Yin, g1, b1, y2, Ybf);
  // ---- stage B: Q projection + V_B projection (512 blocks, 2/CU, one round)
  gemm_qv<<<dim3(32, 16), blk, 0, stream>>>(Ybf, Ebf, W6 + 3 * WSZ, W6 + 5 * WSZ,
                                            QKb, VtB);
  attn_kernel<false><<<dim3(16, 16, 4), blk, 0, stream>>>(QKb, VtB, aout, lens, iscl);
  ln_kernel<<<NB * LS, 256, 0, stream>>>(aout, y2, g2, b2, y3, Ebf);
  // ---- stage C: FFN (8-phase), split-K=4 second GEMM, fused reduce LN
  gemm8<0><<<dim3(16, 16), 512, 131072, stream>>>(Ebf, nullptr, Web, be,
                                                  Hb, nullptr, nullptr, nullptr);
  gemm8<1><<<dim3(16, 4, 4), 512, 131072, stream>>>(Hb, nullptr, Wcb, nullptr,
                                                    part, nullptr, nullptr, nullptr);
  ln_final<<<NB * LS, 256, 0, stream>>>(part, bc, y3, g3, b3, (float*)d_out);
}

// Round 11
// 316.008 us; speedup vs baseline: 1.0126x; 1.0126x over previous
//
#include <hip/hip_runtime.h>
#include <stdint.h>

#define NB 4
#define LS 1024
#define HH 16
#define DHD 64
#define DM 1024
#define DF 4096
#define QKS 2048  // row stride of combined QK activation buffer

typedef unsigned short u16;
typedef __attribute__((ext_vector_type(4))) float f32x4;
typedef __attribute__((ext_vector_type(8))) __bf16 bf16x8;
typedef __attribute__((ext_vector_type(8))) unsigned short u16x8;

__device__ __forceinline__ u16 f2bf(float f) {
  union { float f; uint32_t u; } v; v.f = f;
  uint32_t u = v.u;
  return (u16)((u + 0x7fffu + ((u >> 16) & 1u)) >> 16);
}

__device__ __forceinline__ bf16x8 ldb8(const u16* p) {
  u16x8 r = *(const u16x8*)p;
  return __builtin_bit_cast(bf16x8, r);
}

__device__ __forceinline__ void gload_lds16(const u16* g, u16* l) {
  __builtin_amdgcn_global_load_lds((const __attribute__((address_space(1))) void*)g,
                                   (__attribute__((address_space(3))) void*)l,
                                   16, 0, 0);
}

#define WAITV8() asm volatile("s_waitcnt vmcnt(8)" ::: "memory")
#define WAITV0() asm volatile("s_waitcnt vmcnt(0)" ::: "memory")
#define WAITLGKM() asm volatile("s_waitcnt lgkmcnt(0)" ::: "memory")
#define PHASE_BARRIER()                        \
  do {                                         \
    WAITLGKM();                                \
    __builtin_amdgcn_sched_barrier(0);         \
    __builtin_amdgcn_s_barrier();              \
    __builtin_amdgcn_sched_barrier(0);         \
  } while (0)

// ---------------------------------------------------------------------------
// prep: decode padding_mask (byte/int32/float agnostic). Grid = NB blocks;
// each block scans the shared prefix for the byte-encoding flag (cross-sample
// evidence needed: an all-False sample is ambiguous alone), then counts its
// own sample's non-padded keys.
// ---------------------------------------------------------------------------
__global__ void prep_kernel(const uint32_t* __restrict__ pm, int* lens, float* iscl) {
  __shared__ int flagByte;
  __shared__ int red[256];
  const int tid = threadIdx.x, n = blockIdx.x;
  if (tid == 0) flagByte = 0;
  __syncthreads();
  int f = 0;
  for (int w = tid; w < (NB * LS) / 4; w += 256) {
    uint32_t u = pm[w];
    if (u != 0u && u != 1u && u != 0x3f800000u) f = 1;  // packed-byte pattern
  }
  if (f) atomicOr(&flagByte, 1);
  __syncthreads();
  int c = 0;
  if (flagByte) {
    const uint8_t* pb = (const uint8_t*)pm;
    for (int l = tid; l < LS; l += 256) c += (pb[n * LS + l] == 0) ? 1 : 0;
  } else {
    for (int l = tid; l < LS; l += 256) c += (pm[n * LS + l] == 0) ? 1 : 0;
  }
  red[tid] = c;
  __syncthreads();
  for (int s = 128; s > 0; s >>= 1) {
    if (tid < s) red[tid] += red[tid + s];
    __syncthreads();
  }
  if (tid == 0) { lens[n] = red[0]; iscl[n] = 1.0f / sqrtf((float)red[0]); }
}

// ---------------------------------------------------------------------------
// fused fp32 -> bf16 convert for all 10 tensors (one launch)
// ---------------------------------------------------------------------------
__global__ void cvt_all(const float* s0, u16* d0, const float* s1, u16* d1,
                        const float* s2, u16* d2, const float* s3, u16* d3,
                        const float* s4, u16* d4, const float* s5, u16* d5,
                        const float* s6, u16* d6, const float* s7, u16* d7,
                        const float* s8, u16* d8, const float* s9, u16* d9) {
  const int total = 5767168;  // float4 units
  int i = blockIdx.x * 256 + threadIdx.x;
  for (; i < total; i += gridDim.x * 256) {
    const float* s; u16* d; int j;
    if (i < 1048576)      { s = s0; d = d0; j = i; }
    else if (i < 2097152) { s = s1; d = d1; j = i - 1048576; }
    else if (i < 2359296) { s = s2; d = d2; j = i - 2097152; }
    else if (i < 2621440) { s = s3; d = d3; j = i - 2359296; }
    else if (i < 2883584) { s = s4; d = d4; j = i - 2621440; }
    else if (i < 3145728) { s = s5; d = d5; j = i - 2883584; }
    else if (i < 3407872) { s = s6; d = d6; j = i - 3145728; }
    else if (i < 3670016) { s = s7; d = d7; j = i - 3407872; }
    else if (i < 4718592) { s = s8; d = d8; j = i - 3670016; }
    else                  { s = s9; d = d9; j = i - 4718592; }
    float4 fv = ((const float4*)s)[j];
    ushort4 o;
    o.x = f2bf(fv.x); o.y = f2bf(fv.y); o.z = f2bf(fv.z); o.w = f2bf(fv.w);
    ((ushort4*)d)[j] = o;
  }
}

// ---------------------------------------------------------------------------
// 8-phase 256x256 GEMM: 512 thr (8 waves, 2Mx4N), BK=64 in two k-halves.
// Schedule frozen from R6 (single barrier/phase, counted vmcnt). Grids are
// kept at <=256 blocks (exactly one dispatch round at 1 block/CU).
// MODE 0: FFN1 relu(x+bias)->bf16. MODE 1: FFN2 split-K f32 partial.
// MODE 2: mega projection, 16 bn-tiles (QKa / VtA / QKb K-part).
// ---------------------------------------------------------------------------
template <int MODE>
__global__ __launch_bounds__(512, 2) void gemm8(
    const u16* __restrict__ P0, const u16* __restrict__ P1,
    const u16* __restrict__ PW, const float* __restrict__ bias,
    void* __restrict__ O0, void* __restrict__ O1,
    void* __restrict__ O2, void* __restrict__ O3) {
  extern __shared__ u16 lds[];  // 65536 u16 = 128 KiB
  constexpr int NT = 16;
  const int bm = blockIdx.x;
  const int tid = threadIdx.x;
  const int wid = tid >> 6, lane = tid & 63;
  const int lrow = lane & 15, lgrp = lane >> 4;
  const int wm = wid >> 2, wn = wid & 3;

  const u16* Asrc; const u16* Bsrc; int lda, ldb;
  if constexpr (MODE == 0) {
    Asrc = P0 + (size_t)bm * 256 * DM; lda = DM;
    Bsrc = PW + (size_t)blockIdx.y * 256 * DM; ldb = DM;
  } else if constexpr (MODE == 1) {
    const int z = blockIdx.z;
    Asrc = P0 + (size_t)bm * 256 * DF + z * 1024; lda = DF;
    Bsrc = PW + (size_t)blockIdx.y * 256 * DF + z * 1024; ldb = DF;
  } else {
    const int bnt = blockIdx.y;
    Asrc = (bnt < 12 ? P0 : P1) + (size_t)bm * 256 * DM; lda = DM;
    const int wrow = (bnt < 12) ? bnt * 256 : 4096 + (bnt - 12) * 256;
    Bsrc = PW + (size_t)wrow * DM; ldb = DM;
  }

  int srow[2], skk[2];
#pragma unroll
  for (int i = 0; i < 2; i++) {
    const int c = (i * 8 + wid) * 64 + lane;
    const int pair = c >> 3;
    const int ue = ((c & 7) * 8) ^ ((pair & 7) << 3);
    srow[i] = pair * 2 + (ue >> 5);
    skk[i] = ue & 31;
  }
  const int dslot0 = wid * 512;
  const int dslot1 = (8 + wid) * 512;

  f32x4 acc[2][4][4] = {};

  auto STAGE_A = [&](int kt, int buf, int kh) {
    const int ks = kt < NT ? kt : NT - 1;  // clamped dummy keeps vmcnt uniform
    gload_lds16(Asrc + (size_t)srow[0] * lda + ks * 64 + kh * 32 + skk[0],
                lds + buf * 16384 + kh * 8192 + dslot0);
    gload_lds16(Asrc + (size_t)srow[1] * lda + ks * 64 + kh * 32 + skk[1],
                lds + buf * 16384 + kh * 8192 + dslot1);
  };
  auto STAGE_B = [&](int kt, int buf, int kh) {
    const int ks = kt < NT ? kt : NT - 1;
    gload_lds16(Bsrc + (size_t)srow[0] * ldb + ks * 64 + kh * 32 + skk[0],
                lds + 32768 + buf * 16384 + kh * 8192 + dslot0);
    gload_lds16(Bsrc + (size_t)srow[1] * ldb + ks * 64 + kh * 32 + skk[1],
                lds + 32768 + buf * 16384 + kh * 8192 + dslot1);
  };
  auto LDA = [&](int buf, int kh, int mh, bf16x8* a) {
#pragma unroll
    for (int m = 0; m < 4; m++) {
      const int row = wm * 128 + mh * 64 + m * 16 + lrow;
      const int idx = buf * 16384 + kh * 8192 + (row >> 1) * 64 +
                      ((((row & 1) << 5) + (lgrp << 3)) ^ (((row >> 1) & 7) << 3));
      a[m] = ldb8(lds + idx);
    }
  };
  auto LDB = [&](int buf, int kh, bf16x8* b) {
#pragma unroll
    for (int nn = 0; nn < 4; nn++) {
      const int row = wn * 64 + nn * 16 + lrow;
      const int idx = 32768 + buf * 16384 + kh * 8192 + (row >> 1) * 64 +
                      ((((row & 1) << 5) + (lgrp << 3)) ^ (((row >> 1) & 7) << 3));
      b[nn] = ldb8(lds + idx);
    }
  };
  auto MFMA16 = [&](f32x4 (&a4)[4][4], bf16x8* af, bf16x8* bk) {
    __builtin_amdgcn_s_setprio(1);
#pragma unroll
    for (int m = 0; m < 4; m++)
#pragma unroll
      for (int nn = 0; nn < 4; nn++)
        a4[m][nn] = __builtin_amdgcn_mfma_f32_16x16x32_bf16(af[m], bk[nn], a4[m][nn], 0, 0, 0);
    __builtin_amdgcn_s_setprio(0);
  };

  // prologue: 6 units (tile0 kh0+kh1, tile1 kh0); confirm tile0 kh0 (2 units)
  STAGE_A(0, 0, 0); STAGE_B(0, 0, 0);
  STAGE_A(0, 0, 1); STAGE_B(0, 0, 1);
  STAGE_A(1, 1, 0); STAGE_B(1, 1, 0);
  WAITV8();
  __builtin_amdgcn_s_barrier();
  __builtin_amdgcn_sched_barrier(0);

  for (int t = 0; t < NT; t++) {
    const int b = t & 1;
    bf16x8 af[4], bk[4];
    // ---- P1 (kh0, mh0)
    LDA(b, 0, 0, af); LDB(b, 0, bk);
    STAGE_A(t + 1, b ^ 1, 1);
    PHASE_BARRIER();
    MFMA16(acc[0], af, bk);
    // ---- P2 (kh0, mh1)
    LDA(b, 0, 1, af);
    STAGE_B(t + 1, b ^ 1, 1);
    WAITV8();
    PHASE_BARRIER();
    MFMA16(acc[1], af, bk);
    // ---- P3 (kh1, mh0)
    LDA(b, 1, 0, af); LDB(b, 1, bk);
    STAGE_A(t + 2, b, 0);
    PHASE_BARRIER();
    MFMA16(acc[0], af, bk);
    // ---- P4 (kh1, mh1)
    LDA(b, 1, 1, af);
    STAGE_B(t + 2, b, 0);
    WAITV8();
    PHASE_BARRIER();
    MFMA16(acc[1], af, bk);
  }
  WAITV0();  // drain dummy stages before block exit

  // ---- epilogue
#pragma unroll
  for (int mh = 0; mh < 2; mh++)
#pragma unroll
    for (int m = 0; m < 4; m++) {
      const int grow0 = bm * 256 + wm * 128 + mh * 64 + m * 16 + lgrp * 4;
#pragma unroll
      for (int nn = 0; nn < 4; nn++) {
        const int col_l = wn * 64 + nn * 16 + lrow;
        f32x4 v = acc[mh][m][nn];
        if constexpr (MODE == 0) {
          const int col = blockIdx.y * 256 + col_l;
          const float bv = bias[col];
#pragma unroll
          for (int r = 0; r < 4; r++) {
            float x = v[r] + bv;
            x = x > 0.0f ? x : 0.0f;
            ((u16*)O0)[(size_t)(grow0 + r) * DF + col] = f2bf(x);
          }
        } else if constexpr (MODE == 1) {
          float* C = (float*)O0 + (size_t)blockIdx.z * ((size_t)NB * LS * DM);
          const int col = blockIdx.y * 256 + col_l;
#pragma unroll
          for (int r = 0; r < 4; r++) C[(size_t)(grow0 + r) * DM + col] = v[r];
        } else {
          const int bnt = blockIdx.y;
          const int nidx = grow0 >> 10, l0 = grow0 & 1023;
          if (bnt < 8) {
            const int col = bnt * 256 + col_l;
#pragma unroll
            for (int r = 0; r < 4; r++)
              ((u16*)O0)[(size_t)(grow0 + r) * QKS + col] = f2bf(v[r]);
          } else if (bnt < 12) {
            const int vc = (bnt - 8) * 256 + col_l;
            ushort4 o;
            o.x = f2bf(v[0]); o.y = f2bf(v[1]); o.z = f2bf(v[2]); o.w = f2bf(v[3]);
            *(ushort4*)((u16*)O1 + (((size_t)(nidx * HH + (vc >> 6)) * DHD + (vc & 63)) << 10) + l0) = o;
          } else {
            const int col = 1024 + (bnt - 12) * 256 + col_l;
#pragma unroll
            for (int r = 0; r < 4; r++)
              ((u16*)O2)[(size_t)(grow0 + r) * QKS + col] = f2bf(v[r]);
          }
        }
      }
    }
}

// ---------------------------------------------------------------------------
// Stage-B Q projection + V_B projection in ONE 512-block dispatch (m97 128^2,
// 4 waves, 2 blocks/CU co-resident -> one round).
//   bn < 8 : Q2 = Ybf(post-LN1) @ Wq2^T -> QKb cols 0..1023 (stride QKS)
//   bn >= 8: V_B = Ebf @ Wv2^T -> VtB[n][h][d][l] (transposed per-head)
// ---------------------------------------------------------------------------
__global__ __launch_bounds__(256) void gemm_qv(const u16* __restrict__ Ya,
                                               const u16* __restrict__ Ea,
                                               const u16* __restrict__ Wq,
                                               const u16* __restrict__ Wv,
                                               u16* __restrict__ QKb,
                                               u16* __restrict__ VtB) {
  __shared__ u16 Al[128 * 32];
  __shared__ u16 Bl[128 * 32];
  const int tid = threadIdx.x;
  const int bm = blockIdx.x, bnr = blockIdx.y;
  const bool isV = bnr >= 8;
  const int bn = isV ? bnr - 8 : bnr;
  const int wave = tid >> 6, lane = tid & 63;
  const int lrow = lane & 15, lgrp = lane >> 4;
  const int wr = (wave >> 1) * 64, wc = (wave & 1) * 64;
  f32x4 acc[4][4] = {};
  const u16* Ab = (isV ? Ea : Ya) + (size_t)bm * 128 * DM;
  const u16* Bb = (isV ? Wv : Wq) + (size_t)bn * 128 * DM;
  {
    const int c0 = wave, c1 = wave + 4;
    const int r0 = c0 * 16 + (lane >> 2), r1 = c1 * 16 + (lane >> 2);
    const int scc = (lane & 3) * 8;
    const u16* Ag0 = Ab + (size_t)r0 * DM + scc;
    const u16* Ag1 = Ab + (size_t)r1 * DM + scc;
    const u16* Bg0 = Bb + (size_t)r0 * DM + scc;
    const u16* Bg1 = Bb + (size_t)r1 * DM + scc;
    u16* Ad0 = Al + c0 * 512;
    u16* Ad1 = Al + c1 * 512;
    u16* Bd0 = Bl + c0 * 512;
    u16* Bd1 = Bl + c1 * 512;
    for (int kb = 0; kb < DM; kb += 32) {
      gload_lds16(Ag0, Ad0);
      gload_lds16(Ag1, Ad1);
      gload_lds16(Bg0, Bd0);
      gload_lds16(Bg1, Bd1);
      Ag0 += 32; Ag1 += 32; Bg0 += 32; Bg1 += 32;
      __syncthreads();
      bf16x8 af[4], bfr[4];
#pragma unroll
      for (int m = 0; m < 4; m++) af[m] = ldb8(Al + (wr + m * 16 + lrow) * 32 + lgrp * 8);
#pragma unroll
      for (int nn = 0; nn < 4; nn++) bfr[nn] = ldb8(Bl + (wc + nn * 16 + lrow) * 32 + lgrp * 8);
#pragma unroll
      for (int m = 0; m < 4; m++)
#pragma unroll
        for (int nn = 0; nn < 4; nn++)
          acc[m][nn] = __builtin_amdgcn_mfma_f32_16x16x32_bf16(af[m], bfr[nn], acc[m][nn], 0, 0, 0);
      __syncthreads();
    }
  }
#pragma unroll
  for (int m = 0; m < 4; m++) {
    const int row0 = bm * 128 + wr + m * 16 + lgrp * 4;
    const int nidx = row0 >> 10, l0 = row0 & (LS - 1);
#pragma unroll
    for (int nn = 0; nn < 4; nn++) {
      const int col = bn * 128 + wc + nn * 16 + lrow;
      if (!isV) {
#pragma unroll
        for (int r = 0; r < 4; r++)
          QKb[(size_t)(row0 + r) * QKS + col] = f2bf(acc[m][nn][r]);
      } else {
        const int hh = col >> 6, dd = col & 63;
        ushort4 o;
        o.x = f2bf(acc[m][nn][0]); o.y = f2bf(acc[m][nn][1]);
        o.z = f2bf(acc[m][nn][2]); o.w = f2bf(acc[m][nn][3]);
        *(ushort4*)(VtB + (((size_t)(nidx * HH + hh) * DHD + dd) << 10) + l0) = o;
      }
    }
  }
}

// ---------------------------------------------------------------------------
// Flash attention. Grid (L/64, H, N), 256 threads = 4 waves x 16 q-rows.
// ---------------------------------------------------------------------------
template <bool CAUSAL>
__global__ __launch_bounds__(256) void attn_kernel(const u16* __restrict__ QK,
                                                   const u16* __restrict__ Vt,
                                                   float* __restrict__ Out,
                                                   const int* __restrict__ lens,
                                                   const float* __restrict__ iscl) {
  __shared__ u16 Kl[64 * 72];
  __shared__ u16 Vl[64 * 72];
  __shared__ u16 Pl[4][16 * 72];
  const int n = blockIdx.z, h = blockIdx.y, qb = blockIdx.x * 64;
  const int tid = threadIdx.x, wave = tid >> 6, lane = tid & 63;
  const int lrow = lane & 15, lgrp = lane >> 4;
  const int len = lens[n];
  const float isc = iscl[n];
  const int qrow = qb + wave * 16 + lrow;
  const u16* qptr = QK + ((size_t)(n * LS + qrow)) * QKS + h * DHD + lgrp * 8;
  bf16x8 qf0 = ldb8(qptr);
  bf16x8 qf1 = ldb8(qptr + 32);
  f32x4 oacc[4] = {};
  float m_run[4], l_run[4];
#pragma unroll
  for (int r = 0; r < 4; r++) { m_run[r] = -1e30f; l_run[r] = 0.0f; }
  const int kend = CAUSAL ? (len < qb + 64 ? len : qb + 64) : len;
  const int srow = tid >> 3, sc = (tid & 7) * 8;
  const u16* kg_base = QK + 1024 + ((size_t)(n * LS)) * QKS + h * DHD + sc;
  const u16* vg_base = Vt + ((size_t)((n * HH + h) * DHD) + srow) * LS + sc;
  u16* pw = Pl[wave];
  for (int kb = 0; kb < kend; kb += 64) {
    __syncthreads();
#pragma unroll
    for (int i = 0; i < 2; i++) {
      const int row = srow + i * 32;
      u16x8 kv = *(const u16x8*)(kg_base + (size_t)(kb + row) * QKS);
      *(u16x8*)(Kl + row * 72 + sc) = kv;
      u16x8 vv = *(const u16x8*)(vg_base + (size_t)(i * 32) * LS + kb);
      *(u16x8*)(Vl + row * 72 + sc) = vv;
    }
    __syncthreads();
    f32x4 s[4];
#pragma unroll
    for (int st = 0; st < 4; st++) {
      const u16* kr = Kl + (st * 16 + lrow) * 72 + lgrp * 8;
      bf16x8 kf0 = ldb8(kr);
      bf16x8 kf1 = ldb8(kr + 32);
      f32x4 z = {};
      z = __builtin_amdgcn_mfma_f32_16x16x32_bf16(qf0, kf0, z, 0, 0, 0);
      s[st] = __builtin_amdgcn_mfma_f32_16x16x32_bf16(qf1, kf1, z, 0, 0, 0);
    }
    const int q_r = qb + wave * 16 + lgrp * 4;
#pragma unroll
    for (int st = 0; st < 4; st++) {
      const int k = kb + st * 16 + lrow;
#pragma unroll
      for (int r = 0; r < 4; r++) {
        float v = s[st][r] * isc;
        bool ok = (k < len) && (!CAUSAL || k <= q_r + r);
        s[st][r] = ok ? v : -1e30f;
      }
    }
#pragma unroll
    for (int r = 0; r < 4; r++) {
      float mx = fmaxf(fmaxf(s[0][r], s[1][r]), fmaxf(s[2][r], s[3][r]));
      mx = fmaxf(mx, __shfl_xor(mx, 1));
      mx = fmaxf(mx, __shfl_xor(mx, 2));
      mx = fmaxf(mx, __shfl_xor(mx, 4));
      mx = fmaxf(mx, __shfl_xor(mx, 8));
      float mn = fmaxf(m_run[r], mx);
      float fac = __expf(m_run[r] - mn);
      m_run[r] = mn;
      float sm = 0.0f;
#pragma unroll
      for (int st = 0; st < 4; st++) {
        float p = __expf(s[st][r] - mn);
        s[st][r] = p;
        sm += p;
      }
      sm += __shfl_xor(sm, 1);
      sm += __shfl_xor(sm, 2);
      sm += __shfl_xor(sm, 4);
      sm += __shfl_xor(sm, 8);
      l_run[r] = l_run[r] * fac + sm;
#pragma unroll
      for (int dt = 0; dt < 4; dt++) oacc[dt][r] *= fac;
    }
#pragma unroll
    for (int st = 0; st < 4; st++)
#pragma unroll
      for (int r = 0; r < 4; r++)
        pw[(lgrp * 4 + r) * 72 + st * 16 + lrow] = f2bf(s[st][r]);
#pragma unroll
    for (int ks = 0; ks < 2; ks++) {
      bf16x8 pf = ldb8(pw + lrow * 72 + ks * 32 + lgrp * 8);
#pragma unroll
      for (int dt = 0; dt < 4; dt++) {
        bf16x8 vf = ldb8(Vl + (dt * 16 + lrow) * 72 + ks * 32 + lgrp * 8);
        oacc[dt] = __builtin_amdgcn_mfma_f32_16x16x32_bf16(pf, vf, oacc[dt], 0, 0, 0);
      }
    }
  }
#pragma unroll
  for (int r = 0; r < 4; r++) {
    float inv = 1.0f / l_run[r];
    const int row = qb + wave * 16 + lgrp * 4 + r;
    float* op = Out + ((size_t)(n * LS + row)) * DM + h * DHD;
#pragma unroll
    for (int dt = 0; dt < 4; dt++) op[dt * 16 + lrow] = oacc[dt][r] * inv;
  }
}

// ---------------------------------------------------------------------------
// residual + LayerNorm; emits f32 (next residual) and optional bf16
// ---------------------------------------------------------------------------
__global__ __launch_bounds__(256) void ln_kernel(const float* __restrict__ a,
                                                 const float* __restrict__ res,
                                                 const float* __restrict__ g,
                                                 const float* __restrict__ bta,
                                                 float* __restrict__ outf,
                                                 u16* __restrict__ outb) {
  const int row = blockIdx.x, tid = threadIdx.x;
  float4 x = ((const float4*)(a + (size_t)row * DM))[tid];
  float4 rr = ((const float4*)(res + (size_t)row * DM))[tid];
  x.x += rr.x; x.y += rr.y; x.z += rr.z; x.w += rr.w;
  float s = x.x + x.y + x.z + x.w;
  float s2 = x.x * x.x + x.y * x.y + x.z * x.z + x.w * x.w;
#pragma unroll
  for (int m = 1; m < 64; m <<= 1) { s += __shfl_xor(s, m); s2 += __shfl_xor(s2, m); }
  __shared__ float sm[8];
  const int wv = tid >> 6;
  if ((tid & 63) == 0) { sm[wv] = s; sm[4 + wv] = s2; }
  __syncthreads();
  s = sm[0] + sm[1] + sm[2] + sm[3];
  s2 = sm[4] + sm[5] + sm[6] + sm[7];
  const float mean = s * (1.0f / (float)DM);
  const float var = s2 * (1.0f / (float)DM) - mean * mean;
  const float inv = rsqrtf(var + 1e-5f);
  float4 gg = ((const float4*)g)[tid];
  float4 bb = ((const float4*)bta)[tid];
  float4 y;
  y.x = (x.x - mean) * inv * gg.x + bb.x;
  y.y = (x.y - mean) * inv * gg.y + bb.y;
  y.z = (x.z - mean) * inv * gg.z + bb.z;
  y.w = (x.w - mean) * inv * gg.w + bb.w;
  ((float4*)(outf + (size_t)row * DM))[tid] = y;
  if (outb) {
    ushort4 o;
    o.x = f2bf(y.x); o.y = f2bf(y.y); o.z = f2bf(y.z); o.w = f2bf(y.w);
    ((ushort4*)(outb + (size_t)row * DM))[tid] = o;
  }
}

// ---------------------------------------------------------------------------
// final LN: sums 4 split-K partials + bias + residual, then LayerNorm -> f32
// ---------------------------------------------------------------------------
__global__ __launch_bounds__(256) void ln_final(const float* __restrict__ part,
                                                const float* __restrict__ bias,
                                                const float* __restrict__ res,
                                                const float* __restrict__ g,
                                                const float* __restrict__ bta,
                                                float* __restrict__ outf) {
  const int row = blockIdx.x, tid = threadIdx.x;
  const size_t PS = (size_t)NB * LS * DM;
  float4 x = ((const float4*)(part + (size_t)row * DM))[tid];
  float4 p1 = ((const float4*)(part + PS + (size_t)row * DM))[tid];
  float4 p2 = ((const float4*)(part + 2 * PS + (size_t)row * DM))[tid];
  float4 p3 = ((const float4*)(part + 3 * PS + (size_t)row * DM))[tid];
  float4 bb4 = ((const float4*)bias)[tid];
  float4 rr = ((const float4*)(res + (size_t)row * DM))[tid];
  x.x += p1.x + p2.x + p3.x + bb4.x + rr.x;
  x.y += p1.y + p2.y + p3.y + bb4.y + rr.y;
  x.z += p1.z + p2.z + p3.z + bb4.z + rr.z;
  x.w += p1.w + p2.w + p3.w + bb4.w + rr.w;
  float s = x.x + x.y + x.z + x.w;
  float s2 = x.x * x.x + x.y * x.y + x.z * x.z + x.w * x.w;
#pragma unroll
  for (int m = 1; m < 64; m <<= 1) { s += __shfl_xor(s, m); s2 += __shfl_xor(s2, m); }
  __shared__ float sm[8];
  const int wv = tid >> 6;
  if ((tid & 63) == 0) { sm[wv] = s; sm[4 + wv] = s2; }
  __syncthreads();
  s = sm[0] + sm[1] + sm[2] + sm[3];
  s2 = sm[4] + sm[5] + sm[6] + sm[7];
  const float mean = s * (1.0f / (float)DM);
  const float var = s2 * (1.0f / (float)DM) - mean * mean;
  const float inv = rsqrtf(var + 1e-5f);
  float4 gg = ((const float4*)g)[tid];
  float4 bb = ((const float4*)bta)[tid];
  float4 y;
  y.x = (x.x - mean) * inv * gg.x + bb.x;
  y.y = (x.y - mean) * inv * gg.y + bb.y;
  y.z = (x.z - mean) * inv * gg.z + bb.z;
  y.w = (x.w - mean) * inv * gg.w + bb.w;
  ((float4*)(outf + (size_t)row * DM))[tid] = y;
}

// ---------------------------------------------------------------------------
extern "C" void kernel_launch(void* const* d_in, const int* in_sizes, int n_in,
                              void* d_out, int out_size, void* d_ws, size_t ws_size,
                              hipStream_t stream) {
  const float* enc = (const float*)d_in[0];
  const float* Yin = (const float*)d_in[1];
  const uint32_t* pmask = (const uint32_t*)d_in[3];
  const float* Wq1 = (const float*)d_in[4];
  const float* Wk1 = (const float*)d_in[5];
  const float* Wv1 = (const float*)d_in[6];
  const float* g1 = (const float*)d_in[7];
  const float* b1 = (const float*)d_in[8];
  const float* Wq2 = (const float*)d_in[9];
  const float* Wk2 = (const float*)d_in[10];
  const float* Wv2 = (const float*)d_in[11];
  const float* g2 = (const float*)d_in[12];
  const float* b2 = (const float*)d_in[13];
  const float* We = (const float*)d_in[14];
  const float* be = (const float*)d_in[15];
  const float* Wc = (const float*)d_in[16];
  const float* bc = (const float*)d_in[17];
  const float* g3 = (const float*)d_in[18];
  const float* b3 = (const float*)d_in[19];

  const size_t ACT = (size_t)NB * LS * DM;
  const size_t WSZ = (size_t)DM * DM;
  const size_t WFF = (size_t)DF * DM;
  const size_t HID = (size_t)NB * LS * DF;

  char* ws = (char*)d_ws;
  size_t off = 0;
  auto alloc = [&](size_t bytes) -> void* {
    void* p = ws + off;
    off += (bytes + 255) & ~(size_t)255;
    return p;
  };
  int* lens = (int*)alloc(64);
  float* iscl = (float*)alloc(64);
  u16* Ybf = (u16*)alloc(ACT * 2);
  u16* Ebf = (u16*)alloc(ACT * 2);
  u16* W6 = (u16*)alloc(WSZ * 6 * 2);
  u16* Web = (u16*)alloc(WFF * 2);
  u16* Wcb = (u16*)alloc(WFF * 2);
  size_t region0 = off;
  u16* QKa = (u16*)alloc((size_t)NB * LS * QKS * 2);
  u16* VtA = (u16*)alloc(ACT * 2);
  u16* QKb = (u16*)alloc((size_t)NB * LS * QKS * 2);
  u16* VtB = (u16*)alloc(ACT * 2);
  float* aout = (float*)alloc(ACT * 4);
  float* y2 = (float*)alloc(ACT * 4);
  float* part = (float*)(ws + region0);  // aliases region0 (dead by stage C)
  float* y3 = (float*)alloc(ACT * 4);
  u16* Hb = (u16*)alloc(HID * 2);

  prep_kernel<<<NB, 256, 0, stream>>>(pmask, lens, iscl);
  cvt_all<<<2048, 256, 0, stream>>>(Yin, Ybf, enc, Ebf,
                                    Wq1, W6 + 0 * WSZ, Wk1, W6 + 1 * WSZ,
                                    Wv1, W6 + 2 * WSZ, Wq2, W6 + 3 * WSZ,
                                    Wk2, W6 + 4 * WSZ, Wv2, W6 + 5 * WSZ,
                                    We, Web, Wc, Wcb);

  dim3 blk(256);
  // ---- fused projections: stage-A QKV + stage-B K (256 blocks = one round)
  gemm8<2><<<dim3(16, 16), 512, 131072, stream>>>(Ybf, Ebf, W6, nullptr,
                                                  QKa, VtA, QKb, VtB);
  // ---- stage A: masked self-attention + LN
  attn_kernel<true><<<dim3(16, 16, 4), blk, 0, stream>>>(QKa, VtA, aout, lens, iscl);
  ln_kernel<<<NB * LS, 256, 0, stream>>>(aout, Yin, g1, b1, y2, Ybf);
  // ---- stage B: Q projection + V_B projection (512 blocks, 2/CU, one round)
  gemm_qv<<<dim3(32, 16), blk, 0, stream>>>(Ybf, Ebf, W6 + 3 * WSZ, W6 + 5 * WSZ,
                                            QKb, VtB);
  attn_kernel<false><<<dim3(16, 16, 4), blk, 0, stream>>>(QKb, VtB, aout, lens, iscl);
  ln_kernel<<<NB * LS, 256, 0, stream>>>(aout, y2, g2, b2, y3, Ebf);
  // ---- stage C: FFN (8-phase), split-K=4 second GEMM, fused reduce LN
  gemm8<0><<<dim3(16, 16), 512, 131072, stream>>>(Ebf, nullptr, Web, be,
                                                  Hb, nullptr, nullptr, nullptr);
  gemm8<1><<<dim3(16, 4, 4), 512, 131072, stream>>>(Hb, nullptr, Wcb, nullptr,
                                                    part, nullptr, nullptr, nullptr);
  ln_final<<<NB * LS, 256, 0, stream>>>(part, bc, y3, g3, b3, (float*)d_out);
}

// Round 12
// 297.778 us; speedup vs baseline: 1.0746x; 1.0612x over previous
//
#include <hip/hip_runtime.h>
#include <stdint.h>

#define NB 4
#define LS 1024
#define HH 16
#define DHD 64
#define DM 1024
#define DF 4096
#define QKS 2048  // row stride of combined QK activation buffer

typedef unsigned short u16;
typedef __attribute__((ext_vector_type(4))) float f32x4;
typedef __attribute__((ext_vector_type(8))) __bf16 bf16x8;
typedef __attribute__((ext_vector_type(8))) unsigned short u16x8;

__device__ __forceinline__ u16 f2bf(float f) {
  union { float f; uint32_t u; } v; v.f = f;
  uint32_t u = v.u;
  return (u16)((u + 0x7fffu + ((u >> 16) & 1u)) >> 16);
}

__device__ __forceinline__ bf16x8 ldb8(const u16* p) {
  u16x8 r = *(const u16x8*)p;
  return __builtin_bit_cast(bf16x8, r);
}

__device__ __forceinline__ void gload_lds16(const u16* g, u16* l) {
  __builtin_amdgcn_global_load_lds((const __attribute__((address_space(1))) void*)g,
                                   (__attribute__((address_space(3))) void*)l,
                                   16, 0, 0);
}

#define WAITV8() asm volatile("s_waitcnt vmcnt(8)" ::: "memory")
#define WAITV0() asm volatile("s_waitcnt vmcnt(0)" ::: "memory")
#define WAITLGKM() asm volatile("s_waitcnt lgkmcnt(0)" ::: "memory")
#define PHASE_BARRIER()                        \
  do {                                         \
    WAITLGKM();                                \
    __builtin_amdgcn_sched_barrier(0);         \
    __builtin_amdgcn_s_barrier();              \
    __builtin_amdgcn_sched_barrier(0);         \
  } while (0)

// ---------------------------------------------------------------------------
// prep: decode padding_mask (byte/int32/float agnostic)
// ---------------------------------------------------------------------------
__global__ void prep_kernel(const uint32_t* __restrict__ pm, int* lens, float* iscl) {
  __shared__ int flagByte;
  __shared__ int red[256];
  const int tid = threadIdx.x, n = blockIdx.x;
  if (tid == 0) flagByte = 0;
  __syncthreads();
  int f = 0;
  for (int w = tid; w < (NB * LS) / 4; w += 256) {
    uint32_t u = pm[w];
    if (u != 0u && u != 1u && u != 0x3f800000u) f = 1;  // packed-byte pattern
  }
  if (f) atomicOr(&flagByte, 1);
  __syncthreads();
  int c = 0;
  if (flagByte) {
    const uint8_t* pb = (const uint8_t*)pm;
    for (int l = tid; l < LS; l += 256) c += (pb[n * LS + l] == 0) ? 1 : 0;
  } else {
    for (int l = tid; l < LS; l += 256) c += (pm[n * LS + l] == 0) ? 1 : 0;
  }
  red[tid] = c;
  __syncthreads();
  for (int s = 128; s > 0; s >>= 1) {
    if (tid < s) red[tid] += red[tid + s];
    __syncthreads();
  }
  if (tid == 0) { lens[n] = red[0]; iscl[n] = 1.0f / sqrtf((float)red[0]); }
}

// ---------------------------------------------------------------------------
// fused fp32 -> bf16 convert for all 10 tensors (one launch)
// ---------------------------------------------------------------------------
__global__ void cvt_all(const float* s0, u16* d0, const float* s1, u16* d1,
                        const float* s2, u16* d2, const float* s3, u16* d3,
                        const float* s4, u16* d4, const float* s5, u16* d5,
                        const float* s6, u16* d6, const float* s7, u16* d7,
                        const float* s8, u16* d8, const float* s9, u16* d9) {
  const int total = 5767168;  // float4 units
  int i = blockIdx.x * 256 + threadIdx.x;
  for (; i < total; i += gridDim.x * 256) {
    const float* s; u16* d; int j;
    if (i < 1048576)      { s = s0; d = d0; j = i; }
    else if (i < 2097152) { s = s1; d = d1; j = i - 1048576; }
    else if (i < 2359296) { s = s2; d = d2; j = i - 2097152; }
    else if (i < 2621440) { s = s3; d = d3; j = i - 2359296; }
    else if (i < 2883584) { s = s4; d = d4; j = i - 2621440; }
    else if (i < 3145728) { s = s5; d = d5; j = i - 2883584; }
    else if (i < 3407872) { s = s6; d = d6; j = i - 3145728; }
    else if (i < 3670016) { s = s7; d = d7; j = i - 3407872; }
    else if (i < 4718592) { s = s8; d = d8; j = i - 3670016; }
    else                  { s = s9; d = d9; j = i - 4718592; }
    float4 fv = ((const float4*)s)[j];
    ushort4 o;
    o.x = f2bf(fv.x); o.y = f2bf(fv.y); o.z = f2bf(fv.z); o.w = f2bf(fv.w);
    ((ushort4*)d)[j] = o;
  }
}

// ---------------------------------------------------------------------------
// 8-phase 256x256 GEMM (frozen since R6).
// ---------------------------------------------------------------------------
template <int MODE>
__global__ __launch_bounds__(512, 2) void gemm8(
    const u16* __restrict__ P0, const u16* __restrict__ P1,
    const u16* __restrict__ PW, const float* __restrict__ bias,
    void* __restrict__ O0, void* __restrict__ O1,
    void* __restrict__ O2, void* __restrict__ O3) {
  extern __shared__ u16 lds[];  // 65536 u16 = 128 KiB
  constexpr int NT = 16;
  const int bm = blockIdx.x;
  const int tid = threadIdx.x;
  const int wid = tid >> 6, lane = tid & 63;
  const int lrow = lane & 15, lgrp = lane >> 4;
  const int wm = wid >> 2, wn = wid & 3;

  const u16* Asrc; const u16* Bsrc; int lda, ldb;
  if constexpr (MODE == 0) {
    Asrc = P0 + (size_t)bm * 256 * DM; lda = DM;
    Bsrc = PW + (size_t)blockIdx.y * 256 * DM; ldb = DM;
  } else if constexpr (MODE == 1) {
    const int z = blockIdx.z;
    Asrc = P0 + (size_t)bm * 256 * DF + z * 1024; lda = DF;
    Bsrc = PW + (size_t)blockIdx.y * 256 * DF + z * 1024; ldb = DF;
  } else {
    const int bnt = blockIdx.y;
    Asrc = (bnt < 12 ? P0 : P1) + (size_t)bm * 256 * DM; lda = DM;
    const int wrow = (bnt < 12) ? bnt * 256 : 4096 + (bnt - 12) * 256;
    Bsrc = PW + (size_t)wrow * DM; ldb = DM;
  }

  int srow[2], skk[2];
#pragma unroll
  for (int i = 0; i < 2; i++) {
    const int c = (i * 8 + wid) * 64 + lane;
    const int pair = c >> 3;
    const int ue = ((c & 7) * 8) ^ ((pair & 7) << 3);
    srow[i] = pair * 2 + (ue >> 5);
    skk[i] = ue & 31;
  }
  const int dslot0 = wid * 512;
  const int dslot1 = (8 + wid) * 512;

  f32x4 acc[2][4][4] = {};

  auto STAGE_A = [&](int kt, int buf, int kh) {
    const int ks = kt < NT ? kt : NT - 1;
    gload_lds16(Asrc + (size_t)srow[0] * lda + ks * 64 + kh * 32 + skk[0],
                lds + buf * 16384 + kh * 8192 + dslot0);
    gload_lds16(Asrc + (size_t)srow[1] * lda + ks * 64 + kh * 32 + skk[1],
                lds + buf * 16384 + kh * 8192 + dslot1);
  };
  auto STAGE_B = [&](int kt, int buf, int kh) {
    const int ks = kt < NT ? kt : NT - 1;
    gload_lds16(Bsrc + (size_t)srow[0] * ldb + ks * 64 + kh * 32 + skk[0],
                lds + 32768 + buf * 16384 + kh * 8192 + dslot0);
    gload_lds16(Bsrc + (size_t)srow[1] * ldb + ks * 64 + kh * 32 + skk[1],
                lds + 32768 + buf * 16384 + kh * 8192 + dslot1);
  };
  auto LDA = [&](int buf, int kh, int mh, bf16x8* a) {
#pragma unroll
    for (int m = 0; m < 4; m++) {
      const int row = wm * 128 + mh * 64 + m * 16 + lrow;
      const int idx = buf * 16384 + kh * 8192 + (row >> 1) * 64 +
                      ((((row & 1) << 5) + (lgrp << 3)) ^ (((row >> 1) & 7) << 3));
      a[m] = ldb8(lds + idx);
    }
  };
  auto LDB = [&](int buf, int kh, bf16x8* b) {
#pragma unroll
    for (int nn = 0; nn < 4; nn++) {
      const int row = wn * 64 + nn * 16 + lrow;
      const int idx = 32768 + buf * 16384 + kh * 8192 + (row >> 1) * 64 +
                      ((((row & 1) << 5) + (lgrp << 3)) ^ (((row >> 1) & 7) << 3));
      b[nn] = ldb8(lds + idx);
    }
  };
  auto MFMA16 = [&](f32x4 (&a4)[4][4], bf16x8* af, bf16x8* bk) {
    __builtin_amdgcn_s_setprio(1);
#pragma unroll
    for (int m = 0; m < 4; m++)
#pragma unroll
      for (int nn = 0; nn < 4; nn++)
        a4[m][nn] = __builtin_amdgcn_mfma_f32_16x16x32_bf16(af[m], bk[nn], a4[m][nn], 0, 0, 0);
    __builtin_amdgcn_s_setprio(0);
  };

  STAGE_A(0, 0, 0); STAGE_B(0, 0, 0);
  STAGE_A(0, 0, 1); STAGE_B(0, 0, 1);
  STAGE_A(1, 1, 0); STAGE_B(1, 1, 0);
  WAITV8();
  __builtin_amdgcn_s_barrier();
  __builtin_amdgcn_sched_barrier(0);

  for (int t = 0; t < NT; t++) {
    const int b = t & 1;
    bf16x8 af[4], bk[4];
    LDA(b, 0, 0, af); LDB(b, 0, bk);
    STAGE_A(t + 1, b ^ 1, 1);
    PHASE_BARRIER();
    MFMA16(acc[0], af, bk);
    LDA(b, 0, 1, af);
    STAGE_B(t + 1, b ^ 1, 1);
    WAITV8();
    PHASE_BARRIER();
    MFMA16(acc[1], af, bk);
    LDA(b, 1, 0, af); LDB(b, 1, bk);
    STAGE_A(t + 2, b, 0);
    PHASE_BARRIER();
    MFMA16(acc[0], af, bk);
    LDA(b, 1, 1, af);
    STAGE_B(t + 2, b, 0);
    WAITV8();
    PHASE_BARRIER();
    MFMA16(acc[1], af, bk);
  }
  WAITV0();

#pragma unroll
  for (int mh = 0; mh < 2; mh++)
#pragma unroll
    for (int m = 0; m < 4; m++) {
      const int grow0 = bm * 256 + wm * 128 + mh * 64 + m * 16 + lgrp * 4;
#pragma unroll
      for (int nn = 0; nn < 4; nn++) {
        const int col_l = wn * 64 + nn * 16 + lrow;
        f32x4 v = acc[mh][m][nn];
        if constexpr (MODE == 0) {
          const int col = blockIdx.y * 256 + col_l;
          const float bv = bias[col];
#pragma unroll
          for (int r = 0; r < 4; r++) {
            float x = v[r] + bv;
            x = x > 0.0f ? x : 0.0f;
            ((u16*)O0)[(size_t)(grow0 + r) * DF + col] = f2bf(x);
          }
        } else if constexpr (MODE == 1) {
          float* C = (float*)O0 + (size_t)blockIdx.z * ((size_t)NB * LS * DM);
          const int col = blockIdx.y * 256 + col_l;
#pragma unroll
          for (int r = 0; r < 4; r++) C[(size_t)(grow0 + r) * DM + col] = v[r];
        } else {
          const int bnt = blockIdx.y;
          const int nidx = grow0 >> 10, l0 = grow0 & 1023;
          if (bnt < 8) {
            const int col = bnt * 256 + col_l;
#pragma unroll
            for (int r = 0; r < 4; r++)
              ((u16*)O0)[(size_t)(grow0 + r) * QKS + col] = f2bf(v[r]);
          } else if (bnt < 12) {
            const int vc = (bnt - 8) * 256 + col_l;
            ushort4 o;
            o.x = f2bf(v[0]); o.y = f2bf(v[1]); o.z = f2bf(v[2]); o.w = f2bf(v[3]);
            *(ushort4*)((u16*)O1 + (((size_t)(nidx * HH + (vc >> 6)) * DHD + (vc & 63)) << 10) + l0) = o;
          } else {
            const int col = 1024 + (bnt - 12) * 256 + col_l;
#pragma unroll
            for (int r = 0; r < 4; r++)
              ((u16*)O2)[(size_t)(grow0 + r) * QKS + col] = f2bf(v[r]);
          }
        }
      }
    }
}

// ---------------------------------------------------------------------------
// Stage-B Q projection + V_B projection in ONE 512-block dispatch (frozen).
// ---------------------------------------------------------------------------
__global__ __launch_bounds__(256) void gemm_qv(const u16* __restrict__ Ya,
                                               const u16* __restrict__ Ea,
                                               const u16* __restrict__ Wq,
                                               const u16* __restrict__ Wv,
                                               u16* __restrict__ QKb,
                                               u16* __restrict__ VtB) {
  __shared__ u16 Al[128 * 32];
  __shared__ u16 Bl[128 * 32];
  const int tid = threadIdx.x;
  const int bm = blockIdx.x, bnr = blockIdx.y;
  const bool isV = bnr >= 8;
  const int bn = isV ? bnr - 8 : bnr;
  const int wave = tid >> 6, lane = tid & 63;
  const int lrow = lane & 15, lgrp = lane >> 4;
  const int wr = (wave >> 1) * 64, wc = (wave & 1) * 64;
  f32x4 acc[4][4] = {};
  const u16* Ab = (isV ? Ea : Ya) + (size_t)bm * 128 * DM;
  const u16* Bb = (isV ? Wv : Wq) + (size_t)bn * 128 * DM;
  {
    const int c0 = wave, c1 = wave + 4;
    const int r0 = c0 * 16 + (lane >> 2), r1 = c1 * 16 + (lane >> 2);
    const int scc = (lane & 3) * 8;
    const u16* Ag0 = Ab + (size_t)r0 * DM + scc;
    const u16* Ag1 = Ab + (size_t)r1 * DM + scc;
    const u16* Bg0 = Bb + (size_t)r0 * DM + scc;
    const u16* Bg1 = Bb + (size_t)r1 * DM + scc;
    u16* Ad0 = Al + c0 * 512;
    u16* Ad1 = Al + c1 * 512;
    u16* Bd0 = Bl + c0 * 512;
    u16* Bd1 = Bl + c1 * 512;
    for (int kb = 0; kb < DM; kb += 32) {
      gload_lds16(Ag0, Ad0);
      gload_lds16(Ag1, Ad1);
      gload_lds16(Bg0, Bd0);
      gload_lds16(Bg1, Bd1);
      Ag0 += 32; Ag1 += 32; Bg0 += 32; Bg1 += 32;
      __syncthreads();
      bf16x8 af[4], bfr[4];
#pragma unroll
      for (int m = 0; m < 4; m++) af[m] = ldb8(Al + (wr + m * 16 + lrow) * 32 + lgrp * 8);
#pragma unroll
      for (int nn = 0; nn < 4; nn++) bfr[nn] = ldb8(Bl + (wc + nn * 16 + lrow) * 32 + lgrp * 8);
#pragma unroll
      for (int m = 0; m < 4; m++)
#pragma unroll
        for (int nn = 0; nn < 4; nn++)
          acc[m][nn] = __builtin_amdgcn_mfma_f32_16x16x32_bf16(af[m], bfr[nn], acc[m][nn], 0, 0, 0);
      __syncthreads();
    }
  }
#pragma unroll
  for (int m = 0; m < 4; m++) {
    const int row0 = bm * 128 + wr + m * 16 + lgrp * 4;
    const int nidx = row0 >> 10, l0 = row0 & (LS - 1);
#pragma unroll
    for (int nn = 0; nn < 4; nn++) {
      const int col = bn * 128 + wc + nn * 16 + lrow;
      if (!isV) {
#pragma unroll
        for (int r = 0; r < 4; r++)
          QKb[(size_t)(row0 + r) * QKS + col] = f2bf(acc[m][nn][r]);
      } else {
        const int hh = col >> 6, dd = col & 63;
        ushort4 o;
        o.x = f2bf(acc[m][nn][0]); o.y = f2bf(acc[m][nn][1]);
        o.z = f2bf(acc[m][nn][2]); o.w = f2bf(acc[m][nn][3]);
        *(ushort4*)(VtB + (((size_t)(nidx * HH + hh) * DHD + dd) << 10) + l0) = o;
      }
    }
  }
}

// ---------------------------------------------------------------------------
// Flash attention, SWAPPED QK^T (S^T = mfma(K,Q)): lane owns ONE q-row
// (q = lane&15) with 16 k-values (k = st*16 + lgrp*4 + r). Softmax reduce =
// 15 local fmax + 2 shfl_xor(16,32). P-write: v_cvt_pk_bf16_f32 pairs + b64
// stores (4 consecutive k per lane). T13 defer-max (THR=8) skips the
// rescale/fac-broadcast on most tiles. PV unchanged (P[q][k] LDS layout).
// ---------------------------------------------------------------------------
template <bool CAUSAL>
__global__ __launch_bounds__(256) void attn_kernel(const u16* __restrict__ QK,
                                                   const u16* __restrict__ Vt,
                                                   float* __restrict__ Out,
                                                   const int* __restrict__ lens,
                                                   const float* __restrict__ iscl) {
  __shared__ u16 Kl[64 * 72];
  __shared__ u16 Vl[64 * 72];
  __shared__ u16 Pl[4][16 * 72];
  const int n = blockIdx.z, h = blockIdx.y, qb = blockIdx.x * 64;
  const int tid = threadIdx.x, wave = tid >> 6, lane = tid & 63;
  const int lrow = lane & 15, lgrp = lane >> 4;
  const int len = lens[n];
  const float isc = iscl[n];
  const int qrow = qb + wave * 16 + lrow;  // this lane's q (softmax owner)
  const u16* qptr = QK + ((size_t)(n * LS + qrow)) * QKS + h * DHD + lgrp * 8;
  bf16x8 qf0 = ldb8(qptr);
  bf16x8 qf1 = ldb8(qptr + 32);
  f32x4 oacc[4] = {};        // O[q = wave*16+lgrp*4+r][d = dt*16+lrow]
  float m_run = -1e30f, l_run = 0.0f;  // state for q = qrow
  const int kend = CAUSAL ? (len < qb + 64 ? len : qb + 64) : len;
  const int srow = tid >> 3, sc = (tid & 7) * 8;
  const u16* kg_base = QK + 1024 + ((size_t)(n * LS)) * QKS + h * DHD + sc;
  const u16* vg_base = Vt + ((size_t)((n * HH + h) * DHD) + srow) * LS + sc;
  u16* pw = Pl[wave];
  for (int kb = 0; kb < kend; kb += 64) {
    __syncthreads();
#pragma unroll
    for (int i = 0; i < 2; i++) {
      const int row = srow + i * 32;
      u16x8 kv = *(const u16x8*)(kg_base + (size_t)(kb + row) * QKS);
      *(u16x8*)(Kl + row * 72 + sc) = kv;
      u16x8 vv = *(const u16x8*)(vg_base + (size_t)(i * 32) * LS + kb);
      *(u16x8*)(Vl + row * 72 + sc) = vv;
    }
    __syncthreads();
    // S^T tiles: mfma(A=K, B=Q) -> C[k=lgrp*4+r][q=lrow]
    f32x4 s[4];
#pragma unroll
    for (int st = 0; st < 4; st++) {
      const u16* kr = Kl + (st * 16 + lrow) * 72 + lgrp * 8;
      bf16x8 kf0 = ldb8(kr);
      bf16x8 kf1 = ldb8(kr + 32);
      f32x4 z = {};
      z = __builtin_amdgcn_mfma_f32_16x16x32_bf16(kf0, qf0, z, 0, 0, 0);
      s[st] = __builtin_amdgcn_mfma_f32_16x16x32_bf16(kf1, qf1, z, 0, 0, 0);
    }
    // scale + mask: lane holds S[q=qrow][k = kb + st*16 + lgrp*4 + r]
#pragma unroll
    for (int st = 0; st < 4; st++) {
#pragma unroll
      for (int r = 0; r < 4; r++) {
        const int k = kb + st * 16 + lgrp * 4 + r;
        float v = s[st][r] * isc;
        bool ok = (k < len) && (!CAUSAL || k <= qrow);
        s[st][r] = ok ? v : -1e30f;
      }
    }
    // row max: 15 local fmax + cross-lgrp shfl(16,32)
    float pmax = s[0][0];
#pragma unroll
    for (int st = 0; st < 4; st++)
#pragma unroll
      for (int r = 0; r < 4; r++) pmax = fmaxf(pmax, s[st][r]);
    pmax = fmaxf(pmax, __shfl_xor(pmax, 16));
    pmax = fmaxf(pmax, __shfl_xor(pmax, 32));
    // defer-max (T13): skip rescale when max growth <= 8
    const bool skip = __all(pmax <= m_run + 8.0f);
    float fac = 1.0f;
    if (!skip) {
      float mn = fmaxf(m_run, pmax);
      fac = __expf(m_run - mn);
      m_run = mn;
    }
    float sm = 0.0f;
#pragma unroll
    for (int st = 0; st < 4; st++)
#pragma unroll
      for (int r = 0; r < 4; r++) {
        float p = __expf(s[st][r] - m_run);
        s[st][r] = p;
        sm += p;
      }
    sm += __shfl_xor(sm, 16);
    sm += __shfl_xor(sm, 32);
    l_run = l_run * fac + sm;
    if (!skip) {
      // broadcast fac from the lane owning q' = lgrp*4+r, rescale O
#pragma unroll
      for (int r = 0; r < 4; r++) {
        float fr = __shfl(fac, (lane & 48) | (lgrp * 4 + r));
#pragma unroll
        for (int dt = 0; dt < 4; dt++) oacc[dt][r] *= fr;
      }
    }
    // P -> LDS: lane writes P[q=lrow][k = st*16 + lgrp*4 .. +3] as 2x cvt_pk + b64
#pragma unroll
    for (int st = 0; st < 4; st++) {
      uint32_t w0, w1;
      asm("v_cvt_pk_bf16_f32 %0, %1, %2" : "=v"(w0) : "v"(s[st][0]), "v"(s[st][1]));
      asm("v_cvt_pk_bf16_f32 %0, %1, %2" : "=v"(w1) : "v"(s[st][2]), "v"(s[st][3]));
      uint2 wv; wv.x = w0; wv.y = w1;
      *(uint2*)(pw + lrow * 72 + st * 16 + lgrp * 4) = wv;
    }
    // PV: A = P[q][contiguous k], B = Vl[d][contiguous k]
#pragma unroll
    for (int ks = 0; ks < 2; ks++) {
      bf16x8 pf = ldb8(pw + lrow * 72 + ks * 32 + lgrp * 8);
#pragma unroll
      for (int dt = 0; dt < 4; dt++) {
        bf16x8 vf = ldb8(Vl + (dt * 16 + lrow) * 72 + ks * 32 + lgrp * 8);
        oacc[dt] = __builtin_amdgcn_mfma_f32_16x16x32_bf16(pf, vf, oacc[dt], 0, 0, 0);
      }
    }
  }
  // epilogue: broadcast l_run from owner lane of q' = lgrp*4+r
#pragma unroll
  for (int r = 0; r < 4; r++) {
    float lr = __shfl(l_run, (lane & 48) | (lgrp * 4 + r));
    float inv = 1.0f / lr;
    const int row = qb + wave * 16 + lgrp * 4 + r;
    float* op = Out + ((size_t)(n * LS + row)) * DM + h * DHD;
#pragma unroll
    for (int dt = 0; dt < 4; dt++) op[dt * 16 + lrow] = oacc[dt][r] * inv;
  }
}

// ---------------------------------------------------------------------------
// residual + LayerNorm; emits f32 (next residual) and optional bf16
// ---------------------------------------------------------------------------
__global__ __launch_bounds__(256) void ln_kernel(const float* __restrict__ a,
                                                 const float* __restrict__ res,
                                                 const float* __restrict__ g,
                                                 const float* __restrict__ bta,
                                                 float* __restrict__ outf,
                                                 u16* __restrict__ outb) {
  const int row = blockIdx.x, tid = threadIdx.x;
  float4 x = ((const float4*)(a + (size_t)row * DM))[tid];
  float4 rr = ((const float4*)(res + (size_t)row * DM))[tid];
  x.x += rr.x; x.y += rr.y; x.z += rr.z; x.w += rr.w;
  float s = x.x + x.y + x.z + x.w;
  float s2 = x.x * x.x + x.y * x.y + x.z * x.z + x.w * x.w;
#pragma unroll
  for (int m = 1; m < 64; m <<= 1) { s += __shfl_xor(s, m); s2 += __shfl_xor(s2, m); }
  __shared__ float sm[8];
  const int wv = tid >> 6;
  if ((tid & 63) == 0) { sm[wv] = s; sm[4 + wv] = s2; }
  __syncthreads();
  s = sm[0] + sm[1] + sm[2] + sm[3];
  s2 = sm[4] + sm[5] + sm[6] + sm[7];
  const float mean = s * (1.0f / (float)DM);
  const float var = s2 * (1.0f / (float)DM) - mean * mean;
  const float inv = rsqrtf(var + 1e-5f);
  float4 gg = ((const float4*)g)[tid];
  float4 bb = ((const float4*)bta)[tid];
  float4 y;
  y.x = (x.x - mean) * inv * gg.x + bb.x;
  y.y = (x.y - mean) * inv * gg.y + bb.y;
  y.z = (x.z - mean) * inv * gg.z + bb.z;
  y.w = (x.w - mean) * inv * gg.w + bb.w;
  ((float4*)(outf + (size_t)row * DM))[tid] = y;
  if (outb) {
    ushort4 o;
    o.x = f2bf(y.x); o.y = f2bf(y.y); o.z = f2bf(y.z); o.w = f2bf(y.w);
    ((ushort4*)(outb + (size_t)row * DM))[tid] = o;
  }
}

// ---------------------------------------------------------------------------
// final LN: sums 4 split-K partials + bias + residual, then LayerNorm -> f32
// ---------------------------------------------------------------------------
__global__ __launch_bounds__(256) void ln_final(const float* __restrict__ part,
                                                const float* __restrict__ bias,
                                                const float* __restrict__ res,
                                                const float* __restrict__ g,
                                                const float* __restrict__ bta,
                                                float* __restrict__ outf) {
  const int row = blockIdx.x, tid = threadIdx.x;
  const size_t PS = (size_t)NB * LS * DM;
  float4 x = ((const float4*)(part + (size_t)row * DM))[tid];
  float4 p1 = ((const float4*)(part + PS + (size_t)row * DM))[tid];
  float4 p2 = ((const float4*)(part + 2 * PS + (size_t)row * DM))[tid];
  float4 p3 = ((const float4*)(part + 3 * PS + (size_t)row * DM))[tid];
  float4 bb4 = ((const float4*)bias)[tid];
  float4 rr = ((const float4*)(res + (size_t)row * DM))[tid];
  x.x += p1.x + p2.x + p3.x + bb4.x + rr.x;
  x.y += p1.y + p2.y + p3.y + bb4.y + rr.y;
  x.z += p1.z + p2.z + p3.z + bb4.z + rr.z;
  x.w += p1.w + p2.w + p3.w + bb4.w + rr.w;
  float s = x.x + x.y + x.z + x.w;
  float s2 = x.x * x.x + x.y * x.y + x.z * x.z + x.w * x.w;
#pragma unroll
  for (int m = 1; m < 64; m <<= 1) { s += __shfl_xor(s, m); s2 += __shfl_xor(s2, m); }
  __shared__ float sm[8];
  const int wv = tid >> 6;
  if ((tid & 63) == 0) { sm[wv] = s; sm[4 + wv] = s2; }
  __syncthreads();
  s = sm[0] + sm[1] + sm[2] + sm[3];
  s2 = sm[4] + sm[5] + sm[6] + sm[7];
  const float mean = s * (1.0f / (float)DM);
  const float var = s2 * (1.0f / (float)DM) - mean * mean;
  const float inv = rsqrtf(var + 1e-5f);
  float4 gg = ((const float4*)g)[tid];
  float4 bb = ((const float4*)bta)[tid];
  float4 y;
  y.x = (x.x - mean) * inv * gg.x + bb.x;
  y.y = (x.y - mean) * inv * gg.y + bb.y;
  y.z = (x.z - mean) * inv * gg.z + bb.z;
  y.w = (x.w - mean) * inv * gg.w + bb.w;
  ((float4*)(outf + (size_t)row * DM))[tid] = y;
}

// ---------------------------------------------------------------------------
extern "C" void kernel_launch(void* const* d_in, const int* in_sizes, int n_in,
                              void* d_out, int out_size, void* d_ws, size_t ws_size,
                              hipStream_t stream) {
  const float* enc = (const float*)d_in[0];
  const float* Yin = (const float*)d_in[1];
  const uint32_t* pmask = (const uint32_t*)d_in[3];
  const float* Wq1 = (const float*)d_in[4];
  const float* Wk1 = (const float*)d_in[5];
  const float* Wv1 = (const float*)d_in[6];
  const float* g1 = (const float*)d_in[7];
  const float* b1 = (const float*)d_in[8];
  const float* Wq2 = (const float*)d_in[9];
  const float* Wk2 = (const float*)d_in[10];
  const float* Wv2 = (const float*)d_in[11];
  const float* g2 = (const float*)d_in[12];
  const float* b2 = (const float*)d_in[13];
  const float* We = (const float*)d_in[14];
  const float* be = (const float*)d_in[15];
  const float* Wc = (const float*)d_in[16];
  const float* bc = (const float*)d_in[17];
  const float* g3 = (const float*)d_in[18];
  const float* b3 = (const float*)d_in[19];

  const size_t ACT = (size_t)NB * LS * DM;
  const size_t WSZ = (size_t)DM * DM;
  const size_t WFF = (size_t)DF * DM;
  const size_t HID = (size_t)NB * LS * DF;

  char* ws = (char*)d_ws;
  size_t off = 0;
  auto alloc = [&](size_t bytes) -> void* {
    void* p = ws + off;
    off += (bytes + 255) & ~(size_t)255;
    return p;
  };
  int* lens = (int*)alloc(64);
  float* iscl = (float*)alloc(64);
  u16* Ybf = (u16*)alloc(ACT * 2);
  u16* Ebf = (u16*)alloc(ACT * 2);
  u16* W6 = (u16*)alloc(WSZ * 6 * 2);
  u16* Web = (u16*)alloc(WFF * 2);
  u16* Wcb = (u16*)alloc(WFF * 2);
  size_t region0 = off;
  u16* QKa = (u16*)alloc((size_t)NB * LS * QKS * 2);
  u16* VtA = (u16*)alloc(ACT * 2);
  u16* QKb = (u16*)alloc((size_t)NB * LS * QKS * 2);
  u16* VtB = (u16*)alloc(ACT * 2);
  float* aout = (float*)alloc(ACT * 4);
  float* y2 = (float*)alloc(ACT * 4);
  float* part = (float*)(ws + region0);  // aliases region0 (dead by stage C)
  float* y3 = (float*)alloc(ACT * 4);
  u16* Hb = (u16*)alloc(HID * 2);

  prep_kernel<<<NB, 256, 0, stream>>>(pmask, lens, iscl);
  cvt_all<<<2048, 256, 0, stream>>>(Yin, Ybf, enc, Ebf,
                                    Wq1, W6 + 0 * WSZ, Wk1, W6 + 1 * WSZ,
                                    Wv1, W6 + 2 * WSZ, Wq2, W6 + 3 * WSZ,
                                    Wk2, W6 + 4 * WSZ, Wv2, W6 + 5 * WSZ,
                                    We, Web, Wc, Wcb);

  dim3 blk(256);
  // ---- fused projections: stage-A QKV + stage-B K (256 blocks = one round)
  gemm8<2><<<dim3(16, 16), 512, 131072, stream>>>(Ybf, Ebf, W6, nullptr,
                                                  QKa, VtA, QKb, VtB);
  // ---- stage A: masked self-attention + LN
  attn_kernel<true><<<dim3(16, 16, 4), blk, 0, stream>>>(QKa, VtA, aout, lens, iscl);
  ln_kernel<<<NB * LS, 256, 0, stream>>>(aout, Yin, g1, b1, y2, Ybf);
  // ---- stage B: Q projection + V_B projection (512 blocks, 2/CU, one round)
  gemm_qv<<<dim3(32, 16), blk, 0, stream>>>(Ybf, Ebf, W6 + 3 * WSZ, W6 + 5 * WSZ,
                                            QKb, VtB);
  attn_kernel<false><<<dim3(16, 16, 4), blk, 0, stream>>>(QKb, VtB, aout, lens, iscl);
  ln_kernel<<<NB * LS, 256, 0, stream>>>(aout, y2, g2, b2, y3, Ebf);
  // ---- stage C: FFN (8-phase), split-K=4 second GEMM, fused reduce LN
  gemm8<0><<<dim3(16, 16), 512, 131072, stream>>>(Ebf, nullptr, Web, be,
                                                  Hb, nullptr, nullptr, nullptr);
  gemm8<1><<<dim3(16, 4, 4), 512, 131072, stream>>>(Hb, nullptr, Wcb, nullptr,
                                                    part, nullptr, nullptr, nullptr);
  ln_final<<<NB * LS, 256, 0, stream>>>(part, bc, y3, g3, b3, (float*)d_out);
}

// Round 13
// 287.488 us; speedup vs baseline: 1.1130x; 1.0358x over previous
//
#include <hip/hip_runtime.h>
#include <stdint.h>

#define NB 4
#define LS 1024
#define HH 16
#define DHD 64
#define DM 1024
#define DF 4096
#define QKS 2048  // row stride of combined QK activation buffer
#define LOG2E 1.4426950408889634f

typedef unsigned short u16;
typedef __attribute__((ext_vector_type(4))) float f32x4;
typedef __attribute__((ext_vector_type(8))) __bf16 bf16x8;
typedef __attribute__((ext_vector_type(8))) unsigned short u16x8;

__device__ __forceinline__ u16 f2bf(float f) {
  union { float f; uint32_t u; } v; v.f = f;
  uint32_t u = v.u;
  return (u16)((u + 0x7fffu + ((u >> 16) & 1u)) >> 16);
}

__device__ __forceinline__ bf16x8 ldb8(const u16* p) {
  u16x8 r = *(const u16x8*)p;
  return __builtin_bit_cast(bf16x8, r);
}

__device__ __forceinline__ void gload_lds16(const u16* g, u16* l) {
  __builtin_amdgcn_global_load_lds((const __attribute__((address_space(1))) void*)g,
                                   (__attribute__((address_space(3))) void*)l,
                                   16, 0, 0);
}

#define WAITV8() asm volatile("s_waitcnt vmcnt(8)" ::: "memory")
#define WAITV0() asm volatile("s_waitcnt vmcnt(0)" ::: "memory")
#define WAITLGKM() asm volatile("s_waitcnt lgkmcnt(0)" ::: "memory")
#define PHASE_BARRIER()                        \
  do {                                         \
    WAITLGKM();                                \
    __builtin_amdgcn_sched_barrier(0);         \
    __builtin_amdgcn_s_barrier();              \
    __builtin_amdgcn_sched_barrier(0);         \
  } while (0)

// ---------------------------------------------------------------------------
// prep: decode padding_mask (byte/int32/float agnostic)
// ---------------------------------------------------------------------------
__global__ void prep_kernel(const uint32_t* __restrict__ pm, int* lens, float* iscl) {
  __shared__ int flagByte;
  __shared__ int red[256];
  const int tid = threadIdx.x, n = blockIdx.x;
  if (tid == 0) flagByte = 0;
  __syncthreads();
  int f = 0;
  for (int w = tid; w < (NB * LS) / 4; w += 256) {
    uint32_t u = pm[w];
    if (u != 0u && u != 1u && u != 0x3f800000u) f = 1;  // packed-byte pattern
  }
  if (f) atomicOr(&flagByte, 1);
  __syncthreads();
  int c = 0;
  if (flagByte) {
    const uint8_t* pb = (const uint8_t*)pm;
    for (int l = tid; l < LS; l += 256) c += (pb[n * LS + l] == 0) ? 1 : 0;
  } else {
    for (int l = tid; l < LS; l += 256) c += (pm[n * LS + l] == 0) ? 1 : 0;
  }
  red[tid] = c;
  __syncthreads();
  for (int s = 128; s > 0; s >>= 1) {
    if (tid < s) red[tid] += red[tid + s];
    __syncthreads();
  }
  if (tid == 0) { lens[n] = red[0]; iscl[n] = 1.0f / sqrtf((float)red[0]); }
}

// ---------------------------------------------------------------------------
// fused fp32 -> bf16 convert for all 10 tensors (one launch)
// ---------------------------------------------------------------------------
__global__ void cvt_all(const float* s0, u16* d0, const float* s1, u16* d1,
                        const float* s2, u16* d2, const float* s3, u16* d3,
                        const float* s4, u16* d4, const float* s5, u16* d5,
                        const float* s6, u16* d6, const float* s7, u16* d7,
                        const float* s8, u16* d8, const float* s9, u16* d9) {
  const int total = 5767168;  // float4 units
  int i = blockIdx.x * 256 + threadIdx.x;
  for (; i < total; i += gridDim.x * 256) {
    const float* s; u16* d; int j;
    if (i < 1048576)      { s = s0; d = d0; j = i; }
    else if (i < 2097152) { s = s1; d = d1; j = i - 1048576; }
    else if (i < 2359296) { s = s2; d = d2; j = i - 2097152; }
    else if (i < 2621440) { s = s3; d = d3; j = i - 2359296; }
    else if (i < 2883584) { s = s4; d = d4; j = i - 2621440; }
    else if (i < 3145728) { s = s5; d = d5; j = i - 2883584; }
    else if (i < 3407872) { s = s6; d = d6; j = i - 3145728; }
    else if (i < 3670016) { s = s7; d = d7; j = i - 3407872; }
    else if (i < 4718592) { s = s8; d = d8; j = i - 3670016; }
    else                  { s = s9; d = d9; j = i - 4718592; }
    float4 fv = ((const float4*)s)[j];
    ushort4 o;
    o.x = f2bf(fv.x); o.y = f2bf(fv.y); o.z = f2bf(fv.z); o.w = f2bf(fv.w);
    ((ushort4*)d)[j] = o;
  }
}

// ---------------------------------------------------------------------------
// 8-phase 256x256 GEMM (schedule frozen since R6). MODE 2 additionally
// PRE-SCALES the Q projection (bnt<4) by iscl[n]*log2e so attention can use
// exp2 with no per-element scaling.
// ---------------------------------------------------------------------------
template <int MODE>
__global__ __launch_bounds__(512, 2) void gemm8(
    const u16* __restrict__ P0, const u16* __restrict__ P1,
    const u16* __restrict__ PW, const float* __restrict__ bias,
    void* __restrict__ O0, void* __restrict__ O1,
    void* __restrict__ O2, void* __restrict__ O3,
    const float* __restrict__ iscl) {
  extern __shared__ u16 lds[];  // 65536 u16 = 128 KiB
  constexpr int NT = 16;
  const int bm = blockIdx.x;
  const int tid = threadIdx.x;
  const int wid = tid >> 6, lane = tid & 63;
  const int lrow = lane & 15, lgrp = lane >> 4;
  const int wm = wid >> 2, wn = wid & 3;

  const u16* Asrc; const u16* Bsrc; int lda, ldb;
  if constexpr (MODE == 0) {
    Asrc = P0 + (size_t)bm * 256 * DM; lda = DM;
    Bsrc = PW + (size_t)blockIdx.y * 256 * DM; ldb = DM;
  } else if constexpr (MODE == 1) {
    const int z = blockIdx.z;
    Asrc = P0 + (size_t)bm * 256 * DF + z * 1024; lda = DF;
    Bsrc = PW + (size_t)blockIdx.y * 256 * DF + z * 1024; ldb = DF;
  } else {
    const int bnt = blockIdx.y;
    Asrc = (bnt < 12 ? P0 : P1) + (size_t)bm * 256 * DM; lda = DM;
    const int wrow = (bnt < 12) ? bnt * 256 : 4096 + (bnt - 12) * 256;
    Bsrc = PW + (size_t)wrow * DM; ldb = DM;
  }

  int srow[2], skk[2];
#pragma unroll
  for (int i = 0; i < 2; i++) {
    const int c = (i * 8 + wid) * 64 + lane;
    const int pair = c >> 3;
    const int ue = ((c & 7) * 8) ^ ((pair & 7) << 3);
    srow[i] = pair * 2 + (ue >> 5);
    skk[i] = ue & 31;
  }
  const int dslot0 = wid * 512;
  const int dslot1 = (8 + wid) * 512;

  f32x4 acc[2][4][4] = {};

  auto STAGE_A = [&](int kt, int buf, int kh) {
    const int ks = kt < NT ? kt : NT - 1;
    gload_lds16(Asrc + (size_t)srow[0] * lda + ks * 64 + kh * 32 + skk[0],
                lds + buf * 16384 + kh * 8192 + dslot0);
    gload_lds16(Asrc + (size_t)srow[1] * lda + ks * 64 + kh * 32 + skk[1],
                lds + buf * 16384 + kh * 8192 + dslot1);
  };
  auto STAGE_B = [&](int kt, int buf, int kh) {
    const int ks = kt < NT ? kt : NT - 1;
    gload_lds16(Bsrc + (size_t)srow[0] * ldb + ks * 64 + kh * 32 + skk[0],
                lds + 32768 + buf * 16384 + kh * 8192 + dslot0);
    gload_lds16(Bsrc + (size_t)srow[1] * ldb + ks * 64 + kh * 32 + skk[1],
                lds + 32768 + buf * 16384 + kh * 8192 + dslot1);
  };
  auto LDA = [&](int buf, int kh, int mh, bf16x8* a) {
#pragma unroll
    for (int m = 0; m < 4; m++) {
      const int row = wm * 128 + mh * 64 + m * 16 + lrow;
      const int idx = buf * 16384 + kh * 8192 + (row >> 1) * 64 +
                      ((((row & 1) << 5) + (lgrp << 3)) ^ (((row >> 1) & 7) << 3));
      a[m] = ldb8(lds + idx);
    }
  };
  auto LDB = [&](int buf, int kh, bf16x8* b) {
#pragma unroll
    for (int nn = 0; nn < 4; nn++) {
      const int row = wn * 64 + nn * 16 + lrow;
      const int idx = 32768 + buf * 16384 + kh * 8192 + (row >> 1) * 64 +
                      ((((row & 1) << 5) + (lgrp << 3)) ^ (((row >> 1) & 7) << 3));
      b[nn] = ldb8(lds + idx);
    }
  };
  auto MFMA16 = [&](f32x4 (&a4)[4][4], bf16x8* af, bf16x8* bk) {
    __builtin_amdgcn_s_setprio(1);
#pragma unroll
    for (int m = 0; m < 4; m++)
#pragma unroll
      for (int nn = 0; nn < 4; nn++)
        a4[m][nn] = __builtin_amdgcn_mfma_f32_16x16x32_bf16(af[m], bk[nn], a4[m][nn], 0, 0, 0);
    __builtin_amdgcn_s_setprio(0);
  };

  STAGE_A(0, 0, 0); STAGE_B(0, 0, 0);
  STAGE_A(0, 0, 1); STAGE_B(0, 0, 1);
  STAGE_A(1, 1, 0); STAGE_B(1, 1, 0);
  WAITV8();
  __builtin_amdgcn_s_barrier();
  __builtin_amdgcn_sched_barrier(0);

  for (int t = 0; t < NT; t++) {
    const int b = t & 1;
    bf16x8 af[4], bk[4];
    LDA(b, 0, 0, af); LDB(b, 0, bk);
    STAGE_A(t + 1, b ^ 1, 1);
    PHASE_BARRIER();
    MFMA16(acc[0], af, bk);
    LDA(b, 0, 1, af);
    STAGE_B(t + 1, b ^ 1, 1);
    WAITV8();
    PHASE_BARRIER();
    MFMA16(acc[1], af, bk);
    LDA(b, 1, 0, af); LDB(b, 1, bk);
    STAGE_A(t + 2, b, 0);
    PHASE_BARRIER();
    MFMA16(acc[0], af, bk);
    LDA(b, 1, 1, af);
    STAGE_B(t + 2, b, 0);
    WAITV8();
    PHASE_BARRIER();
    MFMA16(acc[1], af, bk);
  }
  WAITV0();

#pragma unroll
  for (int mh = 0; mh < 2; mh++)
#pragma unroll
    for (int m = 0; m < 4; m++) {
      const int grow0 = bm * 256 + wm * 128 + mh * 64 + m * 16 + lgrp * 4;
#pragma unroll
      for (int nn = 0; nn < 4; nn++) {
        const int col_l = wn * 64 + nn * 16 + lrow;
        f32x4 v = acc[mh][m][nn];
        if constexpr (MODE == 0) {
          const int col = blockIdx.y * 256 + col_l;
          const float bv = bias[col];
#pragma unroll
          for (int r = 0; r < 4; r++) {
            float x = v[r] + bv;
            x = x > 0.0f ? x : 0.0f;
            ((u16*)O0)[(size_t)(grow0 + r) * DF + col] = f2bf(x);
          }
        } else if constexpr (MODE == 1) {
          float* C = (float*)O0 + (size_t)blockIdx.z * ((size_t)NB * LS * DM);
          const int col = blockIdx.y * 256 + col_l;
#pragma unroll
          for (int r = 0; r < 4; r++) C[(size_t)(grow0 + r) * DM + col] = v[r];
        } else {
          const int bnt = blockIdx.y;
          const int nidx = grow0 >> 10, l0 = grow0 & 1023;
          if (bnt < 8) {
            // Q tiles (bnt<4) pre-scaled by iscl[n]*log2e for exp2 softmax
            const float qs = (bnt < 4) ? iscl[nidx] * LOG2E : 1.0f;
            const int col = bnt * 256 + col_l;
#pragma unroll
            for (int r = 0; r < 4; r++)
              ((u16*)O0)[(size_t)(grow0 + r) * QKS + col] = f2bf(v[r] * qs);
          } else if (bnt < 12) {
            const int vc = (bnt - 8) * 256 + col_l;
            ushort4 o;
            o.x = f2bf(v[0]); o.y = f2bf(v[1]); o.z = f2bf(v[2]); o.w = f2bf(v[3]);
            *(ushort4*)((u16*)O1 + (((size_t)(nidx * HH + (vc >> 6)) * DHD + (vc & 63)) << 10) + l0) = o;
          } else {
            const int col = 1024 + (bnt - 12) * 256 + col_l;
#pragma unroll
            for (int r = 0; r < 4; r++)
              ((u16*)O2)[(size_t)(grow0 + r) * QKS + col] = f2bf(v[r]);
          }
        }
      }
    }
}

// ---------------------------------------------------------------------------
// Stage-B Q projection (pre-scaled by iscl*log2e) + V_B projection (frozen).
// ---------------------------------------------------------------------------
__global__ __launch_bounds__(256) void gemm_qv(const u16* __restrict__ Ya,
                                               const u16* __restrict__ Ea,
                                               const u16* __restrict__ Wq,
                                               const u16* __restrict__ Wv,
                                               u16* __restrict__ QKb,
                                               u16* __restrict__ VtB,
                                               const float* __restrict__ iscl) {
  __shared__ u16 Al[128 * 32];
  __shared__ u16 Bl[128 * 32];
  const int tid = threadIdx.x;
  const int bm = blockIdx.x, bnr = blockIdx.y;
  const bool isV = bnr >= 8;
  const int bn = isV ? bnr - 8 : bnr;
  const int wave = tid >> 6, lane = tid & 63;
  const int lrow = lane & 15, lgrp = lane >> 4;
  const int wr = (wave >> 1) * 64, wc = (wave & 1) * 64;
  f32x4 acc[4][4] = {};
  const u16* Ab = (isV ? Ea : Ya) + (size_t)bm * 128 * DM;
  const u16* Bb = (isV ? Wv : Wq) + (size_t)bn * 128 * DM;
  {
    const int c0 = wave, c1 = wave + 4;
    const int r0 = c0 * 16 + (lane >> 2), r1 = c1 * 16 + (lane >> 2);
    const int scc = (lane & 3) * 8;
    const u16* Ag0 = Ab + (size_t)r0 * DM + scc;
    const u16* Ag1 = Ab + (size_t)r1 * DM + scc;
    const u16* Bg0 = Bb + (size_t)r0 * DM + scc;
    const u16* Bg1 = Bb + (size_t)r1 * DM + scc;
    u16* Ad0 = Al + c0 * 512;
    u16* Ad1 = Al + c1 * 512;
    u16* Bd0 = Bl + c0 * 512;
    u16* Bd1 = Bl + c1 * 512;
    for (int kb = 0; kb < DM; kb += 32) {
      gload_lds16(Ag0, Ad0);
      gload_lds16(Ag1, Ad1);
      gload_lds16(Bg0, Bd0);
      gload_lds16(Bg1, Bd1);
      Ag0 += 32; Ag1 += 32; Bg0 += 32; Bg1 += 32;
      __syncthreads();
      bf16x8 af[4], bfr[4];
#pragma unroll
      for (int m = 0; m < 4; m++) af[m] = ldb8(Al + (wr + m * 16 + lrow) * 32 + lgrp * 8);
#pragma unroll
      for (int nn = 0; nn < 4; nn++) bfr[nn] = ldb8(Bl + (wc + nn * 16 + lrow) * 32 + lgrp * 8);
#pragma unroll
      for (int m = 0; m < 4; m++)
#pragma unroll
        for (int nn = 0; nn < 4; nn++)
          acc[m][nn] = __builtin_amdgcn_mfma_f32_16x16x32_bf16(af[m], bfr[nn], acc[m][nn], 0, 0, 0);
      __syncthreads();
    }
  }
#pragma unroll
  for (int m = 0; m < 4; m++) {
    const int row0 = bm * 128 + wr + m * 16 + lgrp * 4;
    const int nidx = row0 >> 10, l0 = row0 & (LS - 1);
#pragma unroll
    for (int nn = 0; nn < 4; nn++) {
      const int col = bn * 128 + wc + nn * 16 + lrow;
      if (!isV) {
        const float qs = iscl[nidx] * LOG2E;
#pragma unroll
        for (int r = 0; r < 4; r++)
          QKb[(size_t)(row0 + r) * QKS + col] = f2bf(acc[m][nn][r] * qs);
      } else {
        const int hh = col >> 6, dd = col & 63;
        ushort4 o;
        o.x = f2bf(acc[m][nn][0]); o.y = f2bf(acc[m][nn][1]);
        o.z = f2bf(acc[m][nn][2]); o.w = f2bf(acc[m][nn][3]);
        *(ushort4*)(VtB + (((size_t)(nidx * HH + hh) * DHD + dd) << 10) + l0) = o;
      }
    }
  }
}

// ---------------------------------------------------------------------------
// Flash attention, swapped QK^T + T14 async-STAGE + exp2 softmax.
// Q is PRE-SCALED by iscl[n]*log2e -> softmax in log2 domain (exp2f, THR
// 11.54 = 8*log2e). K/V tile t+1 is loaded into registers right after tile
// t's LDS write; the vmcnt wait lands at the NEXT iteration's ds_write, so
// HBM latency hides under QK^T/softmax/PV. Mask loop runs only on tail /
// diagonal tiles (wave-uniform branch).
// ---------------------------------------------------------------------------
template <bool CAUSAL>
__global__ __launch_bounds__(256) void attn_kernel(const u16* __restrict__ QK,
                                                   const u16* __restrict__ Vt,
                                                   float* __restrict__ Out,
                                                   const int* __restrict__ lens) {
  __shared__ u16 Kl[64 * 72];
  __shared__ u16 Vl[64 * 72];
  __shared__ u16 Pl[4][16 * 72];
  const int n = blockIdx.z, h = blockIdx.y, qb = blockIdx.x * 64;
  const int tid = threadIdx.x, wave = tid >> 6, lane = tid & 63;
  const int lrow = lane & 15, lgrp = lane >> 4;
  const int len = lens[n];
  const int qrow = qb + wave * 16 + lrow;  // this lane's q (softmax owner)
  const u16* qptr = QK + ((size_t)(n * LS + qrow)) * QKS + h * DHD + lgrp * 8;
  bf16x8 qf0 = ldb8(qptr);
  bf16x8 qf1 = ldb8(qptr + 32);
  f32x4 oacc[4] = {};        // O[q = wave*16+lgrp*4+r][d = dt*16+lrow]
  float m_run = -1e30f, l_run = 0.0f;  // state for q = qrow (log2 domain)
  const int kend = CAUSAL ? (len < qb + 64 ? len : qb + 64) : len;
  const int srow = tid >> 3, sc = (tid & 7) * 8;
  const u16* kg_base = QK + 1024 + ((size_t)(n * LS)) * QKS + h * DHD + sc;
  const u16* vg_base = Vt + ((size_t)((n * HH + h) * DHD) + srow) * LS + sc;
  u16* pw = Pl[wave];
  u16x8 kreg[2], vreg[2];
  auto LOADKV = [&](int kb) {
#pragma unroll
    for (int i = 0; i < 2; i++) {
      kreg[i] = *(const u16x8*)(kg_base + (size_t)(kb + srow + i * 32) * QKS);
      vreg[i] = *(const u16x8*)(vg_base + (size_t)(i * 32) * LS + kb);
    }
  };
  LOADKV(0);
  for (int kb = 0; kb < kend; kb += 64) {
    __syncthreads();  // prev-tile LDS consumers done
#pragma unroll
    for (int i = 0; i < 2; i++) {  // implicit vmcnt wait on kreg/vreg here
      *(u16x8*)(Kl + (srow + i * 32) * 72 + sc) = kreg[i];
      *(u16x8*)(Vl + (srow + i * 32) * 72 + sc) = vreg[i];
    }
    __syncthreads();
    if (kb + 64 < kend) LOADKV(kb + 64);  // issue next tile early (T14)
    // S^T tiles: mfma(A=K, B=Q) -> lane holds S[q=qrow][k=kb+st*16+lgrp*4+r]
    f32x4 s[4];
#pragma unroll
    for (int st = 0; st < 4; st++) {
      const u16* kr = Kl + (st * 16 + lrow) * 72 + lgrp * 8;
      bf16x8 kf0 = ldb8(kr);
      bf16x8 kf1 = ldb8(kr + 32);
      f32x4 z = {};
      z = __builtin_amdgcn_mfma_f32_16x16x32_bf16(kf0, qf0, z, 0, 0, 0);
      s[st] = __builtin_amdgcn_mfma_f32_16x16x32_bf16(kf1, qf1, z, 0, 0, 0);
    }
    // mask only on tail / diagonal tiles (wave-uniform branch)
    const bool needMask = (kb + 64 > len) || (CAUSAL && (kb + 64 > qb + wave * 16));
    if (needMask) {
#pragma unroll
      for (int st = 0; st < 4; st++)
#pragma unroll
        for (int r = 0; r < 4; r++) {
          const int k = kb + st * 16 + lgrp * 4 + r;
          bool ok = (k < len) && (!CAUSAL || k <= qrow);
          s[st][r] = ok ? s[st][r] : -1e30f;
        }
    }
    // row max: 15 local fmax + cross-lgrp shfl(16,32)
    float pmax = s[0][0];
#pragma unroll
    for (int st = 0; st < 4; st++)
#pragma unroll
      for (int r = 0; r < 4; r++) pmax = fmaxf(pmax, s[st][r]);
    pmax = fmaxf(pmax, __shfl_xor(pmax, 16));
    pmax = fmaxf(pmax, __shfl_xor(pmax, 32));
    // defer-max (T13, log2 domain: THR = 8*log2e)
    const bool skip = __all(pmax <= m_run + 11.541560327f);
    float fac = 1.0f;
    if (!skip) {
      float mn = fmaxf(m_run, pmax);
      fac = exp2f(m_run - mn);
      m_run = mn;
    }
    float sm = 0.0f;
#pragma unroll
    for (int st = 0; st < 4; st++)
#pragma unroll
      for (int r = 0; r < 4; r++) {
        float p = exp2f(s[st][r] - m_run);
        s[st][r] = p;
        sm += p;
      }
    sm += __shfl_xor(sm, 16);
    sm += __shfl_xor(sm, 32);
    l_run = l_run * fac + sm;
    if (!skip) {
#pragma unroll
      for (int r = 0; r < 4; r++) {
        float fr = __shfl(fac, (lane & 48) | (lgrp * 4 + r));
#pragma unroll
        for (int dt = 0; dt < 4; dt++) oacc[dt][r] *= fr;
      }
    }
    // P -> LDS: 2x cvt_pk + b64 per st
#pragma unroll
    for (int st = 0; st < 4; st++) {
      uint32_t w0, w1;
      asm("v_cvt_pk_bf16_f32 %0, %1, %2" : "=v"(w0) : "v"(s[st][0]), "v"(s[st][1]));
      asm("v_cvt_pk_bf16_f32 %0, %1, %2" : "=v"(w1) : "v"(s[st][2]), "v"(s[st][3]));
      uint2 wv; wv.x = w0; wv.y = w1;
      *(uint2*)(pw + lrow * 72 + st * 16 + lgrp * 4) = wv;
    }
    // PV: A = P[q][contiguous k], B = Vl[d][contiguous k]
#pragma unroll
    for (int ks = 0; ks < 2; ks++) {
      bf16x8 pf = ldb8(pw + lrow * 72 + ks * 32 + lgrp * 8);
#pragma unroll
      for (int dt = 0; dt < 4; dt++) {
        bf16x8 vf = ldb8(Vl + (dt * 16 + lrow) * 72 + ks * 32 + lgrp * 8);
        oacc[dt] = __builtin_amdgcn_mfma_f32_16x16x32_bf16(pf, vf, oacc[dt], 0, 0, 0);
      }
    }
  }
  // epilogue: broadcast l_run from owner lane of q' = lgrp*4+r
#pragma unroll
  for (int r = 0; r < 4; r++) {
    float lr = __shfl(l_run, (lane & 48) | (lgrp * 4 + r));
    float inv = 1.0f / lr;
    const int row = qb + wave * 16 + lgrp * 4 + r;
    float* op = Out + ((size_t)(n * LS + row)) * DM + h * DHD;
#pragma unroll
    for (int dt = 0; dt < 4; dt++) op[dt * 16 + lrow] = oacc[dt][r] * inv;
  }
}

// ---------------------------------------------------------------------------
// residual + LayerNorm; emits f32 (next residual) and optional bf16
// ---------------------------------------------------------------------------
__global__ __launch_bounds__(256) void ln_kernel(const float* __restrict__ a,
                                                 const float* __restrict__ res,
                                                 const float* __restrict__ g,
                                                 const float* __restrict__ bta,
                                                 float* __restrict__ outf,
                                                 u16* __restrict__ outb) {
  const int row = blockIdx.x, tid = threadIdx.x;
  float4 x = ((const float4*)(a + (size_t)row * DM))[tid];
  float4 rr = ((const float4*)(res + (size_t)row * DM))[tid];
  x.x += rr.x; x.y += rr.y; x.z += rr.z; x.w += rr.w;
  float s = x.x + x.y + x.z + x.w;
  float s2 = x.x * x.x + x.y * x.y + x.z * x.z + x.w * x.w;
#pragma unroll
  for (int m = 1; m < 64; m <<= 1) { s += __shfl_xor(s, m); s2 += __shfl_xor(s2, m); }
  __shared__ float sm[8];
  const int wv = tid >> 6;
  if ((tid & 63) == 0) { sm[wv] = s; sm[4 + wv] = s2; }
  __syncthreads();
  s = sm[0] + sm[1] + sm[2] + sm[3];
  s2 = sm[4] + sm[5] + sm[6] + sm[7];
  const float mean = s * (1.0f / (float)DM);
  const float var = s2 * (1.0f / (float)DM) - mean * mean;
  const float inv = rsqrtf(var + 1e-5f);
  float4 gg = ((const float4*)g)[tid];
  float4 bb = ((const float4*)bta)[tid];
  float4 y;
  y.x = (x.x - mean) * inv * gg.x + bb.x;
  y.y = (x.y - mean) * inv * gg.y + bb.y;
  y.z = (x.z - mean) * inv * gg.z + bb.z;
  y.w = (x.w - mean) * inv * gg.w + bb.w;
  ((float4*)(outf + (size_t)row * DM))[tid] = y;
  if (outb) {
    ushort4 o;
    o.x = f2bf(y.x); o.y = f2bf(y.y); o.z = f2bf(y.z); o.w = f2bf(y.w);
    ((ushort4*)(outb + (size_t)row * DM))[tid] = o;
  }
}

// ---------------------------------------------------------------------------
// final LN: sums 4 split-K partials + bias + residual, then LayerNorm -> f32
// ---------------------------------------------------------------------------
__global__ __launch_bounds__(256) void ln_final(const float* __restrict__ part,
                                                const float* __restrict__ bias,
                                                const float* __restrict__ res,
                                                const float* __restrict__ g,
                                                const float* __restrict__ bta,
                                                float* __restrict__ outf) {
  const int row = blockIdx.x, tid = threadIdx.x;
  const size_t PS = (size_t)NB * LS * DM;
  float4 x = ((const float4*)(part + (size_t)row * DM))[tid];
  float4 p1 = ((const float4*)(part + PS + (size_t)row * DM))[tid];
  float4 p2 = ((const float4*)(part + 2 * PS + (size_t)row * DM))[tid];
  float4 p3 = ((const float4*)(part + 3 * PS + (size_t)row * DM))[tid];
  float4 bb4 = ((const float4*)bias)[tid];
  float4 rr = ((const float4*)(res + (size_t)row * DM))[tid];
  x.x += p1.x + p2.x + p3.x + bb4.x + rr.x;
  x.y += p1.y + p2.y + p3.y + bb4.y + rr.y;
  x.z += p1.z + p2.z + p3.z + bb4.z + rr.z;
  x.w += p1.w + p2.w + p3.w + bb4.w + rr.w;
  float s = x.x + x.y + x.z + x.w;
  float s2 = x.x * x.x + x.y * x.y + x.z * x.z + x.w * x.w;
#pragma unroll
  for (int m = 1; m < 64; m <<= 1) { s += __shfl_xor(s, m); s2 += __shfl_xor(s2, m); }
  __shared__ float sm[8];
  const int wv = tid >> 6;
  if ((tid & 63) == 0) { sm[wv] = s; sm[4 + wv] = s2; }
  __syncthreads();
  s = sm[0] + sm[1] + sm[2] + sm[3];
  s2 = sm[4] + sm[5] + sm[6] + sm[7];
  const float mean = s * (1.0f / (float)DM);
  const float var = s2 * (1.0f / (float)DM) - mean * mean;
  const float inv = rsqrtf(var + 1e-5f);
  float4 gg = ((const float4*)g)[tid];
  float4 bb = ((const float4*)bta)[tid];
  float4 y;
  y.x = (x.x - mean) * inv * gg.x + bb.x;
  y.y = (x.y - mean) * inv * gg.y + bb.y;
  y.z = (x.z - mean) * inv * gg.z + bb.z;
  y.w = (x.w - mean) * inv * gg.w + bb.w;
  ((float4*)(outf + (size_t)row * DM))[tid] = y;
}

// ---------------------------------------------------------------------------
extern "C" void kernel_launch(void* const* d_in, const int* in_sizes, int n_in,
                              void* d_out, int out_size, void* d_ws, size_t ws_size,
                              hipStream_t stream) {
  const float* enc = (const float*)d_in[0];
  const float* Yin = (const float*)d_in[1];
  const uint32_t* pmask = (const uint32_t*)d_in[3];
  const float* Wq1 = (const float*)d_in[4];
  const float* Wk1 = (const float*)d_in[5];
  const float* Wv1 = (const float*)d_in[6];
  const float* g1 = (const float*)d_in[7];
  const float* b1 = (const float*)d_in[8];
  const float* Wq2 = (const float*)d_in[9];
  const float* Wk2 = (const float*)d_in[10];
  const float* Wv2 = (const float*)d_in[11];
  const float* g2 = (const float*)d_in[12];
  const float* b2 = (const float*)d_in[13];
  const float* We = (const float*)d_in[14];
  const float* be = (const float*)d_in[15];
  const float* Wc = (const float*)d_in[16];
  const float* bc = (const float*)d_in[17];
  const float* g3 = (const float*)d_in[18];
  const float* b3 = (const float*)d_in[19];

  const size_t ACT = (size_t)NB * LS * DM;
  const size_t WSZ = (size_t)DM * DM;
  const size_t WFF = (size_t)DF * DM;
  const size_t HID = (size_t)NB * LS * DF;

  char* ws = (char*)d_ws;
  size_t off = 0;
  auto alloc = [&](size_t bytes) -> void* {
    void* p = ws + off;
    off += (bytes + 255) & ~(size_t)255;
    return p;
  };
  int* lens = (int*)alloc(64);
  float* iscl = (float*)alloc(64);
  u16* Ybf = (u16*)alloc(ACT * 2);
  u16* Ebf = (u16*)alloc(ACT * 2);
  u16* W6 = (u16*)alloc(WSZ * 6 * 2);
  u16* Web = (u16*)alloc(WFF * 2);
  u16* Wcb = (u16*)alloc(WFF * 2);
  size_t region0 = off;
  u16* QKa = (u16*)alloc((size_t)NB * LS * QKS * 2);
  u16* VtA = (u16*)alloc(ACT * 2);
  u16* QKb = (u16*)alloc((size_t)NB * LS * QKS * 2);
  u16* VtB = (u16*)alloc(ACT * 2);
  float* aout = (float*)alloc(ACT * 4);
  float* y2 = (float*)alloc(ACT * 4);
  float* part = (float*)(ws + region0);  // aliases region0 (dead by stage C)
  float* y3 = (float*)alloc(ACT * 4);
  u16* Hb = (u16*)alloc(HID * 2);

  prep_kernel<<<NB, 256, 0, stream>>>(pmask, lens, iscl);
  cvt_all<<<2048, 256, 0, stream>>>(Yin, Ybf, enc, Ebf,
                                    Wq1, W6 + 0 * WSZ, Wk1, W6 + 1 * WSZ,
                                    Wv1, W6 + 2 * WSZ, Wq2, W6 + 3 * WSZ,
                                    Wk2, W6 + 4 * WSZ, Wv2, W6 + 5 * WSZ,
                                    We, Web, Wc, Wcb);

  dim3 blk(256);
  // ---- fused projections: stage-A QKV + stage-B K (256 blocks = one round)
  gemm8<2><<<dim3(16, 16), 512, 131072, stream>>>(Ybf, Ebf, W6, nullptr,
                                                  QKa, VtA, QKb, VtB, iscl);
  // ---- stage A: masked self-attention + LN
  attn_kernel<true><<<dim3(16, 16, 4), blk, 0, stream>>>(QKa, VtA, aout, lens);
  ln_kernel<<<NB * LS, 256, 0, stream>>>(aout, Yin, g1, b1, y2, Ybf);
  // ---- stage B: Q projection + V_B projection (512 blocks, 2/CU, one round)
  gemm_qv<<<dim3(32, 16), blk, 0, stream>>>(Ybf, Ebf, W6 + 3 * WSZ, W6 + 5 * WSZ,
                                            QKb, VtB, iscl);
  attn_kernel<false><<<dim3(16, 16, 4), blk, 0, stream>>>(QKb, VtB, aout, lens);
  ln_kernel<<<NB * LS, 256, 0, stream>>>(aout, y2, g2, b2, y3, Ebf);
  // ---- stage C: FFN (8-phase), split-K=4 second GEMM, fused reduce LN
  gemm8<0><<<dim3(16, 16), 512, 131072, stream>>>(Ebf, nullptr, Web, be,
                                                  Hb, nullptr, nullptr, nullptr, nullptr);
  gemm8<1><<<dim3(16, 4, 4), 512, 131072, stream>>>(Hb, nullptr, Wcb, nullptr,
                                                    part, nullptr, nullptr, nullptr, nullptr);
  ln_final<<<NB * LS, 256, 0, stream>>>(part, bc, y3, g3, b3, (float*)d_out);
}